// Round 1
// 538.789 us; speedup vs baseline: 1.2070x; 1.2070x over previous
//
#include <hip/hip_runtime.h>

#define DIM 256
#define N_REL 8

typedef __attribute__((ext_vector_type(8))) short short8_t;
typedef __attribute__((ext_vector_type(4))) float float4_t;

// ---------------- bf16 helpers (manual, RNE) ----------------
__device__ inline unsigned short f2bf(float f) {
    unsigned u = __float_as_uint(f);
    u += 0x7FFFu + ((u >> 16) & 1u);
    return (unsigned short)(u >> 16);
}
__device__ inline float bf2f(unsigned short h) {
    return __uint_as_float(((unsigned)h) << 16);
}

// ---------------- cast / transpose prep kernels ----------------
__global__ __launch_bounds__(256) void cast_f32_bf16(
    const float* __restrict__ in, unsigned short* __restrict__ out, int n4)
{
    const int i = blockIdx.x * blockDim.x + threadIdx.x;
    if (i >= n4) return;
    const float4 v = ((const float4*)in)[i];
    ushort4 o;
    o.x = f2bf(v.x); o.y = f2bf(v.y); o.z = f2bf(v.z); o.w = f2bf(v.w);
    ((ushort4*)out)[i] = o;
}

// W[rel][in][out] f32  ->  Wt[rel][out][in] bf16
__global__ __launch_bounds__(256) void transpose_cast_w(
    const float* __restrict__ W, unsigned short* __restrict__ Wt)
{
    __shared__ float tile[32][33];
    const int rel = blockIdx.z;
    const int i0 = blockIdx.x * 32, o0 = blockIdx.y * 32;
    const int tx = threadIdx.x, ty = threadIdx.y;   // (32, 8)
    const float* Wr = W + (size_t)rel * DIM * DIM;
    unsigned short* Wtr = Wt + (size_t)rel * DIM * DIM;
#pragma unroll
    for (int j = 0; j < 4; j++)
        tile[ty + 8 * j][tx] = Wr[(size_t)(i0 + ty + 8 * j) * DIM + o0 + tx];
    __syncthreads();
#pragma unroll
    for (int j = 0; j < 4; j++)
        Wtr[(size_t)(o0 + ty + 8 * j) * DIM + i0 + tx] = f2bf(tile[tx][ty + 8 * j]);
}

// ---------------------------------------------------------------------------
// Yall[rel][M][256] = relu(Xb @ W[rel] + bias) in bf16.
// Tile 128x128, BK=32, 4 waves of 64x64 (4x4 mfma_f32_16x16x32_bf16).
// 1-D grid, octet swizzle: row-tile rt = (L>>7)*8 | (L&7) pins each rt to one
// XCD across all 16 (ntile, rel) combos -> A-tile fetched once per XCD
// (R6: FETCH 214MB = 8x full A; expect ~35MB).
// Epilogue staged through LDS -> full 256B coalesced row-segment stores.
// NOTE: epilogue mi-loop MUST be fully unrolled: a runtime index into acc[]
// demotes the accumulator to scratch (R4/R5: 3.7 GB WRITE_SIZE, VGPR 88->64).
// ---------------------------------------------------------------------------
__global__ __launch_bounds__(256) void gemm_mfma_bias_relu(
    const unsigned short* __restrict__ Xb,    // [M][256]
    const unsigned short* __restrict__ Wtb,   // [R][256out][256in]
    const float* __restrict__ bias,           // [256]
    unsigned short* __restrict__ Yall, int M, int Rtiles)
{
    __shared__ __align__(16) short smem[10240]; // As 5120 | Bs 5120 shorts
    short* As = smem;
    short* Bs = smem + 5120;

    const unsigned L = blockIdx.x;
    const int xcd = L & 7;
    const unsigned g = L >> 3;
    const int combo = g & 15;                 // (ntile, rel)
    const int rt = (int)((g >> 4) << 3) | xcd;
    if (rt >= Rtiles) return;
    const int m0 = rt * 128;
    const int n0 = (combo & 1) * 128;
    const int rel = combo >> 1;

    const unsigned short* Wt = Wtb + (size_t)rel * DIM * DIM;
    unsigned short* Y = Yall + (size_t)rel * M * DIM;

    const int t = threadIdx.x;
    const int lane = t & 63;
    const int w = t >> 6;
    const int wr = w & 1, wc = w >> 1;
    const int r = lane & 15, q = lane >> 4;

    const int rowA0 = t >> 2;     // 0..63 (+64 second half)
    const int segA0 = t & 3;      // 16B segment within 64B row

    float4_t acc[4][4];
#pragma unroll
    for (int i = 0; i < 4; i++)
#pragma unroll
        for (int j = 0; j < 4; j++) {
            float4_t z = {0.f, 0.f, 0.f, 0.f};
            acc[i][j] = z;
        }

    short8_t ra[2], rb[2];
    const short8_t zero8 = {0, 0, 0, 0, 0, 0, 0, 0};

#define LOAD_TILES(ks)                                                            \
    {                                                                             \
        const int k0_ = (ks) * 32;                                                \
        _Pragma("unroll")                                                         \
        for (int h = 0; h < 2; h++) {                                             \
            const int row_ = rowA0 + h * 64;                                      \
            const int m_ = m0 + row_;                                             \
            if (m_ < M)                                                           \
                ra[h] = *(const short8_t*)(Xb + (size_t)m_ * DIM + k0_ + segA0 * 8); \
            else                                                                  \
                ra[h] = zero8;                                                    \
            rb[h] = *(const short8_t*)(Wt + (size_t)(n0 + row_) * DIM + k0_ + segA0 * 8); \
        }                                                                         \
    }

    LOAD_TILES(0);
#pragma unroll 1
    for (int ks = 0; ks < 8; ks++) {
#pragma unroll
        for (int h = 0; h < 2; h++) {
            const int row_ = rowA0 + h * 64;
            *(short8_t*)&As[row_ * 40 + segA0 * 8] = ra[h];
            *(short8_t*)&Bs[row_ * 40 + segA0 * 8] = rb[h];
        }
        __syncthreads();
        if (ks < 7) LOAD_TILES(ks + 1);

        short8_t af[4], bf[4];
#pragma unroll
        for (int mi = 0; mi < 4; mi++)
            af[mi] = *(const short8_t*)&As[(wr * 64 + mi * 16 + r) * 40 + q * 8];
#pragma unroll
        for (int ni = 0; ni < 4; ni++)
            bf[ni] = *(const short8_t*)&Bs[(wc * 64 + ni * 16 + r) * 40 + q * 8];
#pragma unroll
        for (int mi = 0; mi < 4; mi++)
#pragma unroll
            for (int ni = 0; ni < 4; ni++)
                acc[mi][ni] = __builtin_amdgcn_mfma_f32_16x16x32_bf16(
                    af[mi], bf[ni], acc[mi][ni], 0, 0, 0);
        __syncthreads();
    }
#undef LOAD_TILES

    // -------- epilogue: bias+relu, LDS-staged coalesced bf16 stores --------
    short* St = smem;   // 32*136 = 4352 shorts, aliases As/Bs (K-loop done)

    float bv[4];
#pragma unroll
    for (int ni = 0; ni < 4; ni++)
        bv[ni] = bias[n0 + wc * 64 + ni * 16 + r];

#pragma unroll
    for (int mi = 0; mi < 4; mi++) {
#pragma unroll
        for (int ni = 0; ni < 4; ni++) {
#pragma unroll
            for (int e = 0; e < 4; e++) {
                const int rl = wr * 16 + q * 4 + e;
                const int col = wc * 64 + ni * 16 + r;
                St[rl * 136 + col] = f2bf(fmaxf(acc[mi][ni][e] + bv[ni], 0.f));
            }
        }
        __syncthreads();
        // readout: 512 chunks of 8 shorts (16B); each thread stores 2
#pragma unroll
        for (int j = 0; j < 2; j++) {
            const int id = t + 256 * j;
            const int rl = id >> 4;        // 0..31
            const int ch = id & 15;        // 0..15
            const int grow = m0 + (rl >> 4) * 64 + mi * 16 + (rl & 15);
            const short8_t v = *(const short8_t*)&St[rl * 136 + ch * 8];
            if (grow < M)
                *(short8_t*)&Y[(size_t)grow * DIM + n0 + ch * 8] = v;
        }
        __syncthreads();
    }
}

// ---------------- CSR build: histogram -> 3-phase scan -> fill ----------------
__global__ __launch_bounds__(256) void count_dst(
    const int* __restrict__ dst, int E, int* __restrict__ cnt)
{
    const int e = blockIdx.x * blockDim.x + threadIdx.x;
    if (e < E) atomicAdd(&cnt[dst[e]], 1);
}

// Phase 1: block b reduces cnt[b*1024 .. b*1024+1023] -> bsum[b].
// (R7: replaces the single-workgroup scan_counts -- 110 us at 0.14% occupancy,
//  pure one-CU latency walk. 3-phase scan spreads the 600 KB across the grid.)
__global__ __launch_bounds__(256) void scan_blocksums(
    const int* __restrict__ cnt, int N, int* __restrict__ bsum)
{
    __shared__ int red[256];
    const int t = threadIdx.x;
    const int base = blockIdx.x * 1024 + t * 4;
    int s = 0;
#pragma unroll
    for (int j = 0; j < 4; j++) {
        const int i = base + j;
        if (i < N) s += cnt[i];
    }
    red[t] = s;
    __syncthreads();
#pragma unroll
    for (int off = 128; off > 0; off >>= 1) {
        if (t < off) red[t] += red[t + off];
        __syncthreads();
    }
    if (t == 0) bsum[blockIdx.x] = red[0];
}

// Phase 2: single tiny block scans bsum[0..nb) (nb <= 64 for M < 65536)
// -> exclusive block offsets in-place; total -> rowptr[N].
__global__ __launch_bounds__(256) void scan_offsets(
    int* __restrict__ bsum, int nb, int* __restrict__ rowptr, int N)
{
    __shared__ int sh[256];
    const int t = threadIdx.x;
    sh[t] = (t < nb) ? bsum[t] : 0;
    __syncthreads();
    for (int off = 1; off < 256; off <<= 1) {
        const int add = (t >= off) ? sh[t - off] : 0;
        __syncthreads();
        sh[t] += add;
        __syncthreads();
    }
    if (t < nb) bsum[t] = (t == 0) ? 0 : sh[t - 1];
    if (t == 255) rowptr[N] = sh[255];
}

// Phase 3: block b rescans its 1024 cnts, adds bsum[b], writes rowptr+cursor.
__global__ __launch_bounds__(256) void scan_phase3(
    const int* __restrict__ cnt, int N, const int* __restrict__ bsum,
    int* __restrict__ rowptr, int* __restrict__ cursor)
{
    __shared__ int sh[256];
    const int t = threadIdx.x;
    const int base = blockIdx.x * 1024 + t * 4;
    int v[4];
#pragma unroll
    for (int j = 0; j < 4; j++) {
        const int i = base + j;
        v[j] = (i < N) ? cnt[i] : 0;
    }
    sh[t] = v[0] + v[1] + v[2] + v[3];
    __syncthreads();
    for (int off = 1; off < 256; off <<= 1) {
        const int add = (t >= off) ? sh[t - off] : 0;
        __syncthreads();
        sh[t] += add;
        __syncthreads();
    }
    int run = bsum[blockIdx.x] + ((t == 0) ? 0 : sh[t - 1]);
#pragma unroll
    for (int j = 0; j < 4; j++) {
        const int i = base + j;
        if (i < N) { rowptr[i] = run; cursor[i] = run; }
        run += v[j];
    }
}

__global__ __launch_bounds__(256) void fill_edges(
    const int* __restrict__ src, const int* __restrict__ dst,
    const int* __restrict__ et, int E, int* __restrict__ cursor,
    unsigned* __restrict__ ep)
{
    const int e = blockIdx.x * blockDim.x + threadIdx.x;
    if (e >= E) return;
    const int pos = atomicAdd(&cursor[dst[e]], 1);
    ep[pos] = (unsigned)src[e] | ((unsigned)et[e] << 16);
}

// -------- aggregate: gather + sum, 2 edges/wave, unroll x2 for MLP ---------
template <typename OT>
__global__ __launch_bounds__(256) void aggregate4(
    const unsigned short* __restrict__ yall,   // [R][M][256]
    const unsigned* __restrict__ ep, const int* __restrict__ rowptr,
    OT* __restrict__ out, int M)
{
    const int lane = threadIdx.x & 63;
    const int half = lane >> 5;     // which edge of a pair
    const int cl = lane & 31;       // 8-short chunk within message row
    const int wv = (blockIdx.x * blockDim.x + threadIdx.x) >> 6;
    const int nw = (gridDim.x * blockDim.x) >> 6;
    const size_t plane = (size_t)M * DIM;

    for (int d = wv; d < M; d += nw) {
        const int beg = rowptr[d], end = rowptr[d + 1];
        float acc[8];
#pragma unroll
        for (int j = 0; j < 8; j++) acc[j] = 0.f;

        for (int c0 = beg; c0 < end; c0 += 64) {
            const int n = min(64, end - c0);
            const unsigned myep = (c0 + lane < end) ? ep[c0 + lane] : 0u;
            // 4 edges per iteration: each half-wave issues 2 independent loads
            for (int i = 0; i < n; i += 4) {
                const int i0 = i + half;
                const int i1 = i + 2 + half;
                const unsigned p0 = __shfl(myep, i0 & 63);
                const unsigned p1 = __shfl(myep, i1 & 63);
                // loads always address-safe (myep==0 for OOB lanes)
                const short8_t u0 = *(const short8_t*)(
                    yall + (size_t)(p0 >> 16) * plane +
                    (size_t)(p0 & 0xFFFFu) * DIM + cl * 8);
                const short8_t u1 = *(const short8_t*)(
                    yall + (size_t)(p1 >> 16) * plane +
                    (size_t)(p1 & 0xFFFFu) * DIM + cl * 8);
                if (i0 < n) {
#pragma unroll
                    for (int j = 0; j < 8; j++)
                        acc[j] += bf2f((unsigned short)u0[j]);
                }
                if (i1 < n) {
#pragma unroll
                    for (int j = 0; j < 8; j++)
                        acc[j] += bf2f((unsigned short)u1[j]);
                }
            }
        }
        // fold the two halves: lane l (<32) adds lane l+32's accumulator
        float o[8];
#pragma unroll
        for (int j = 0; j < 8; j++)
            o[j] = acc[j] + __shfl(acc[j], (lane + 32) & 63);
        if (lane < 32) {
            OT* dp = out + (size_t)d * DIM + cl * 8;
            if (sizeof(OT) == 4) {
                *(float4*)((float*)dp) = make_float4(o[0], o[1], o[2], o[3]);
                *(float4*)((float*)dp + 4) = make_float4(o[4], o[5], o[6], o[7]);
            } else {
                short8_t v;
#pragma unroll
                for (int j = 0; j < 8; j++) v[j] = (short)f2bf(o[j]);
                *(short8_t*)((unsigned short*)dp) = v;
            }
        }
    }
}

// ---------------- fallback: fp32 vector GEMM + atomic scatter ----------------
__global__ __launch_bounds__(256) void gemm_bias_relu_f32(
    const float* __restrict__ A, const float* __restrict__ B,
    const float* __restrict__ bias, float* __restrict__ Y, int M)
{
    __shared__ float Asf[16][132];
    __shared__ float Bsf[16][128];
    const int t = threadIdx.x;
    const int tx = t & 15, ty = t >> 4;
    const int row0 = blockIdx.x * 128, col0 = blockIdx.y * 128;
    float acc[8][8];
#pragma unroll
    for (int i = 0; i < 8; i++)
#pragma unroll
        for (int j = 0; j < 8; j++) acc[i][j] = 0.f;
    const int arow = t >> 2, akseg = (t & 3) * 4;
    const int bk0 = t >> 5, bcol = (t & 31) * 4;
    for (int k0 = 0; k0 < DIM; k0 += 16) {
#pragma unroll
        for (int h = 0; h < 2; h++) {
            const int row = row0 + arow + h * 64;
            float4 av = (row < M) ? *(const float4*)(A + (size_t)row * DIM + k0 + akseg)
                                  : make_float4(0, 0, 0, 0);
            Asf[akseg + 0][arow + h * 64] = av.x;
            Asf[akseg + 1][arow + h * 64] = av.y;
            Asf[akseg + 2][arow + h * 64] = av.z;
            Asf[akseg + 3][arow + h * 64] = av.w;
        }
#pragma unroll
        for (int h = 0; h < 2; h++) {
            const int krow = bk0 + h * 8;
            *(float4*)&Bsf[krow][bcol] =
                *(const float4*)(B + (size_t)(k0 + krow) * DIM + col0 + bcol);
        }
        __syncthreads();
#pragma unroll
        for (int k = 0; k < 16; k++) {
            float a[8], b[8];
            *(float4*)&a[0] = *(const float4*)&Asf[k][ty * 4];
            *(float4*)&a[4] = *(const float4*)&Asf[k][64 + ty * 4];
            *(float4*)&b[0] = *(const float4*)&Bsf[k][tx * 4];
            *(float4*)&b[4] = *(const float4*)&Bsf[k][64 + tx * 4];
#pragma unroll
            for (int i = 0; i < 8; i++)
#pragma unroll
                for (int j = 0; j < 8; j++) acc[i][j] = fmaf(a[i], b[j], acc[i][j]);
        }
        __syncthreads();
    }
#pragma unroll
    for (int im = 0; im < 2; im++)
#pragma unroll
        for (int i = 0; i < 4; i++) {
            const int row = row0 + im * 64 + ty * 4 + i;
            if (row >= M) continue;
#pragma unroll
            for (int jm = 0; jm < 2; jm++) {
                const int col = col0 + jm * 64 + tx * 4;
                const float4 bb = *(const float4*)(bias + col);
                float4 o;
                o.x = fmaxf(acc[im * 4 + i][jm * 4 + 0] + bb.x, 0.f);
                o.y = fmaxf(acc[im * 4 + i][jm * 4 + 1] + bb.y, 0.f);
                o.z = fmaxf(acc[im * 4 + i][jm * 4 + 2] + bb.z, 0.f);
                o.w = fmaxf(acc[im * 4 + i][jm * 4 + 3] + bb.w, 0.f);
                *(float4*)(Y + (size_t)row * DIM + col) = o;
            }
        }
}

__global__ __launch_bounds__(256) void scatter_rel(
    const float* __restrict__ y, const int* __restrict__ src,
    const int* __restrict__ dst, const int* __restrict__ et,
    int rel, float* __restrict__ out, int n_edges)
{
    const int lane = threadIdx.x & 63;
    const int wave = (blockIdx.x * blockDim.x + threadIdx.x) >> 6;
    const int nwaves = (gridDim.x * blockDim.x) >> 6;
    for (int e = wave; e < n_edges; e += nwaves) {
        if (et[e] != rel) continue;
        const float4 v = *(const float4*)(y + (size_t)src[e] * DIM + lane * 4);
        float* o = out + (size_t)dst[e] * DIM + lane * 4;
        atomicAdd(o + 0, v.x);
        atomicAdd(o + 1, v.y);
        atomicAdd(o + 2, v.z);
        atomicAdd(o + 3, v.w);
    }
}

static inline size_t align16(size_t x) { return (x + 15) & ~(size_t)15; }

extern "C" void kernel_launch(void* const* d_in, const int* in_sizes, int n_in,
                              void* d_out, int out_size, void* d_ws, size_t ws_size,
                              hipStream_t stream)
{
    const float* x  = (const float*)d_in[0];
    const float* W0 = (const float*)d_in[1];
    const float* b0 = (const float*)d_in[2];
    const float* W1 = (const float*)d_in[3];
    const float* b1 = (const float*)d_in[4];
    const int* eidx = (const int*)d_in[5];
    const int* etyp = (const int*)d_in[6];

    const int M = in_sizes[0] / DIM;   // 50000
    const int E = in_sizes[6];         // 800000
    const int* src = eidx;
    const int* dst = eidx + E;
    float* out = (float*)d_out;

    const size_t plane = (size_t)M * DIM;
    const size_t wbytes = (size_t)N_REL * DIM * DIM * 2;

    const size_t need = align16(plane * 2)              // h1b
                      + align16(plane * 2)              // xb
                      + 2 * align16(wbytes)             // Wt0b, Wt1b
                      + align16((size_t)(M + 1) * 4)    // rowptr
                      + 2 * align16((size_t)M * 4)      // cnt, cursor
                      + align16((size_t)256 * 4)        // bsum (block sums)
                      + align16((size_t)E * 4)          // ep
                      + align16((size_t)N_REL * plane * 2);  // yall

    if (M < 65536 && ws_size >= need) {
        char* ws = (char*)d_ws;
        size_t off = 0;
        unsigned short* h1b  = (unsigned short*)(ws + off); off = align16(off + plane * 2);
        unsigned short* xb   = (unsigned short*)(ws + off); off = align16(off + plane * 2);
        unsigned short* Wt0b = (unsigned short*)(ws + off); off = align16(off + wbytes);
        unsigned short* Wt1b = (unsigned short*)(ws + off); off = align16(off + wbytes);
        int* rowptr = (int*)(ws + off); off = align16(off + (size_t)(M + 1) * 4);
        int* cnt    = (int*)(ws + off); off = align16(off + (size_t)M * 4);
        int* cursor = (int*)(ws + off); off = align16(off + (size_t)M * 4);
        int* bsum   = (int*)(ws + off); off = align16(off + (size_t)256 * 4);
        unsigned* ep = (unsigned*)(ws + off); off = align16(off + (size_t)E * 4);
        unsigned short* yall = (unsigned short*)(ws + off);

        // CSR build (shared by both layers). 3-phase parallel scan:
        // R7: the old single-workgroup scan_counts was 110 us (17% of total)
        // at 0.14% occupancy -- one CU walking 600 KB at memory latency.
        const int nb = (M + 1023) / 1024;   // <= 64 blocks for M < 65536
        hipMemsetAsync(cnt, 0, (size_t)M * 4, stream);
        count_dst<<<(E + 255) / 256, 256, 0, stream>>>(dst, E, cnt);
        scan_blocksums<<<nb, 256, 0, stream>>>(cnt, M, bsum);
        scan_offsets<<<1, 256, 0, stream>>>(bsum, nb, rowptr, M);
        scan_phase3<<<nb, 256, 0, stream>>>(cnt, M, bsum, rowptr, cursor);
        fill_edges<<<(E + 255) / 256, 256, 0, stream>>>(src, dst, etyp, E, cursor, ep);

        // prep: casts / transposes
        cast_f32_bf16<<<(int)((plane / 4 + 255) / 256), 256, 0, stream>>>(
            x, xb, (int)(plane / 4));
        transpose_cast_w<<<dim3(8, 8, N_REL), dim3(32, 8), 0, stream>>>(W0, Wt0b);
        transpose_cast_w<<<dim3(8, 8, N_REL), dim3(32, 8), 0, stream>>>(W1, Wt1b);

        const int Rtiles = (M + 127) / 128;
        const int octets = (Rtiles + 7) / 8;
        const int ggrid = octets * 16 * 8;
        const int agrid = (int)(((size_t)M * 64 + 255) / 256); // 1 wave/dst

        // layer 1
        gemm_mfma_bias_relu<<<ggrid, 256, 0, stream>>>(xb, Wt0b, b0, yall, M, Rtiles);
        aggregate4<unsigned short><<<agrid, 256, 0, stream>>>(yall, ep, rowptr, h1b, M);
        // layer 2
        gemm_mfma_bias_relu<<<ggrid, 256, 0, stream>>>(h1b, Wt1b, b1, yall, M, Rtiles);
        aggregate4<float><<<agrid, 256, 0, stream>>>(yall, ep, rowptr, out, M);
    } else {
        // fallback: fp32 per-relation GEMM + atomic scatter
        float* h1 = (float*)d_ws;
        float* y  = (float*)d_ws + plane;
        const dim3 gblk(256), ggrid2((M + 127) / 128, DIM / 128);
        hipMemsetAsync(h1, 0, plane * 4, stream);
        for (int r = 0; r < N_REL; r++) {
            gemm_bias_relu_f32<<<ggrid2, gblk, 0, stream>>>(
                x, W0 + (size_t)r * DIM * DIM, b0, y, M);
            scatter_rel<<<1024, 256, 0, stream>>>(y, src, dst, etyp, r, h1, E);
        }
        hipMemsetAsync(out, 0, plane * 4, stream);
        for (int r = 0; r < N_REL; r++) {
            gemm_bias_relu_f32<<<ggrid2, gblk, 0, stream>>>(
                h1, W1 + (size_t)r * DIM * DIM, b1, y, M);
            scatter_rel<<<1024, 256, 0, stream>>>(y, src, dst, etyp, r, out, E);
        }
    }
}

// Round 2
// 509.963 us; speedup vs baseline: 1.2752x; 1.0565x over previous
//
#include <hip/hip_runtime.h>

#define DIM 256
#define N_REL 8

typedef __attribute__((ext_vector_type(8))) short short8_t;
typedef __attribute__((ext_vector_type(4))) float float4_t;

// ---------------- bf16 helpers (manual, RNE) ----------------
__device__ inline unsigned short f2bf(float f) {
    unsigned u = __float_as_uint(f);
    u += 0x7FFFu + ((u >> 16) & 1u);
    return (unsigned short)(u >> 16);
}
__device__ inline float bf2f(unsigned short h) {
    return __uint_as_float(((unsigned)h) << 16);
}

// ---------------- cast / transpose prep kernels ----------------
__global__ __launch_bounds__(256) void cast_f32_bf16(
    const float* __restrict__ in, unsigned short* __restrict__ out, int n4)
{
    const int i = blockIdx.x * blockDim.x + threadIdx.x;
    if (i >= n4) return;
    const float4 v = ((const float4*)in)[i];
    ushort4 o;
    o.x = f2bf(v.x); o.y = f2bf(v.y); o.z = f2bf(v.z); o.w = f2bf(v.w);
    ((ushort4*)out)[i] = o;
}

// W[rel][in][out] f32  ->  Wt[rel][out][in] bf16
__global__ __launch_bounds__(256) void transpose_cast_w(
    const float* __restrict__ W, unsigned short* __restrict__ Wt)
{
    __shared__ float tile[32][33];
    const int rel = blockIdx.z;
    const int i0 = blockIdx.x * 32, o0 = blockIdx.y * 32;
    const int tx = threadIdx.x, ty = threadIdx.y;   // (32, 8)
    const float* Wr = W + (size_t)rel * DIM * DIM;
    unsigned short* Wtr = Wt + (size_t)rel * DIM * DIM;
#pragma unroll
    for (int j = 0; j < 4; j++)
        tile[ty + 8 * j][tx] = Wr[(size_t)(i0 + ty + 8 * j) * DIM + o0 + tx];
    __syncthreads();
#pragma unroll
    for (int j = 0; j < 4; j++)
        Wtr[(size_t)(o0 + ty + 8 * j) * DIM + i0 + tx] = f2bf(tile[tx][ty + 8 * j]);
}

// ---------------------------------------------------------------------------
// Yall[rel][M][256] = relu(Xb @ W[rel] + bias) in bf16.
// Tile 128x128, BK=32, 4 waves of 64x64 (4x4 mfma_f32_16x16x32_bf16).
// R8: K-loop restructured to global_load_lds width=16 (direct HBM->LDS DMA,
// no reg staging / no ds_write), double-buffered linear LDS [row][64B] with
// XOR segment swizzle seg^=(row>>1)&3 applied BOTH to the global source addr
// and the ds_read offset (rule 21) -> 2-way (free) bank pattern on reads.
// Counted s_waitcnt vmcnt(4) + raw s_barrier per K-step keeps next tile's 4
// loads/wave in flight across the barrier (no full __syncthreads drain).
// (R7 counters: VALUBusy 32% staging-bound, LDS_BANK_CONFLICT 1.36e7,
//  MfmaUtil 21.7% -> staging was the limiter, not MFMA or HBM.)
// OOB A-rows of the last tile load garbage (in-workspace) but those acc rows
// are never stored (grow<M guard).
// 1-D grid, octet swizzle: rt = (L>>7)*8 | (L&7) pins each row-tile to one
// XCD across all 16 (ntile, rel) combos -> A fetched ~once (FETCH 19.5MB).
// Epilogue staged through LDS -> full 256B coalesced row-segment stores.
// NOTE: epilogue mi-loop MUST be fully unrolled: a runtime index into acc[]
// demotes the accumulator to scratch (R4/R5: 3.7 GB WRITE_SIZE, VGPR 88->64).
// ---------------------------------------------------------------------------
__global__ __launch_bounds__(256) void gemm_mfma_bias_relu(
    const unsigned short* __restrict__ Xb,    // [M][256]
    const unsigned short* __restrict__ Wtb,   // [R][256out][256in]
    const float* __restrict__ bias,           // [256]
    unsigned short* __restrict__ Yall, int M, int Rtiles)
{
    // buf0: As 0..4095 | Bs 4096..8191 ; buf1: As 8192.. | Bs 12288.. (shorts)
    __shared__ __align__(16) short smem[16384];   // 32 KiB

    const unsigned L = blockIdx.x;
    const int xcd = L & 7;
    const unsigned g = L >> 3;
    const int combo = g & 15;                 // (ntile, rel)
    const int rt = (int)((g >> 4) << 3) | xcd;
    if (rt >= Rtiles) return;
    const int m0 = rt * 128;
    const int n0 = (combo & 1) * 128;
    const int rel = combo >> 1;

    const unsigned short* Wt = Wtb + (size_t)rel * DIM * DIM;
    unsigned short* Y = Yall + (size_t)rel * M * DIM;

    const int t = threadIdx.x;
    const int lane = t & 63;
    const int w = t >> 6;
    const int wr = w & 1, wc = w >> 1;
    const int r = lane & 15, q = lane >> 4;

    // ---- staging geometry: chunk c = h*256 + w*64 + lane, c=(row*4+slot) ----
    const int sl = lane & 3;            // 16B slot within 64B row
    const int rsub = lane >> 2;         // 0..15
    const unsigned short* gA[2];
    const unsigned short* gB[2];
#pragma unroll
    for (int h = 0; h < 2; h++) {
        const int row = h * 64 + w * 16 + rsub;          // 0..127
        const int gseg = sl ^ ((row >> 1) & 3);          // pre-swizzled source
        gA[h] = Xb + (size_t)(m0 + row) * DIM + gseg * 8;
        gB[h] = Wt + (size_t)(n0 + row) * DIM + gseg * 8;
    }

    // ---- fragment read offsets (shorts), constant across K-steps ----
    const int swz = (q ^ ((r >> 1) & 3)) * 8;            // swizzled k-segment
    int offA[4], offB[4];
#pragma unroll
    for (int mi = 0; mi < 4; mi++)
        offA[mi] = (wr * 64 + mi * 16 + r) * 32 + swz;
#pragma unroll
    for (int ni = 0; ni < 4; ni++)
        offB[ni] = (wc * 64 + ni * 16 + r) * 32 + swz;

    float4_t acc[4][4];
#pragma unroll
    for (int i = 0; i < 4; i++)
#pragma unroll
        for (int j = 0; j < 4; j++) {
            float4_t z = {0.f, 0.f, 0.f, 0.f};
            acc[i][j] = z;
        }

    // 4 global_load_lds per wave per K-step (2 A + 2 B), each 16B/lane.
#define STAGE(ks, bsel)                                                         \
    {                                                                           \
        const int k0_ = (ks) * 32;                                              \
        short* Ad_ = smem + ((bsel) ? 8192 : 0);                                \
        short* Bd_ = Ad_ + 4096;                                                \
        _Pragma("unroll")                                                       \
        for (int h = 0; h < 2; h++) {                                           \
            __builtin_amdgcn_global_load_lds(                                   \
                (const __attribute__((address_space(1))) unsigned int*)(gA[h] + k0_), \
                (__attribute__((address_space(3))) unsigned int*)(Ad_ + h * 2048 + w * 512), \
                16, 0, 0);                                                      \
            __builtin_amdgcn_global_load_lds(                                   \
                (const __attribute__((address_space(1))) unsigned int*)(gB[h] + k0_), \
                (__attribute__((address_space(3))) unsigned int*)(Bd_ + h * 2048 + w * 512), \
                16, 0, 0);                                                      \
        }                                                                       \
    }

    STAGE(0, 0);
#pragma unroll 1
    for (int ks = 0; ks < 8; ks++) {
        const int cur = ks & 1;
        if (ks < 7) {
            STAGE(ks + 1, cur ^ 1);
            asm volatile("s_waitcnt vmcnt(4)" ::: "memory");
        } else {
            asm volatile("s_waitcnt vmcnt(0)" ::: "memory");
        }
        asm volatile("s_barrier" ::: "memory");

        const short* As_b = smem + (cur ? 8192 : 0);
        const short* Bs_b = As_b + 4096;
        short8_t af[4], bf[4];
#pragma unroll
        for (int mi = 0; mi < 4; mi++)
            af[mi] = *(const short8_t*)&As_b[offA[mi]];
#pragma unroll
        for (int ni = 0; ni < 4; ni++)
            bf[ni] = *(const short8_t*)&Bs_b[offB[ni]];
#pragma unroll
        for (int mi = 0; mi < 4; mi++)
#pragma unroll
            for (int ni = 0; ni < 4; ni++)
                acc[mi][ni] = __builtin_amdgcn_mfma_f32_16x16x32_bf16(
                    af[mi], bf[ni], acc[mi][ni], 0, 0, 0);
        asm volatile("s_barrier" ::: "memory");
    }
#undef STAGE

    // -------- epilogue: bias+relu, LDS-staged coalesced bf16 stores --------
    short* St = smem;   // 32*136 = 4352 shorts, aliases buf0 (K-loop done)

    float bv[4];
#pragma unroll
    for (int ni = 0; ni < 4; ni++)
        bv[ni] = bias[n0 + wc * 64 + ni * 16 + r];

#pragma unroll
    for (int mi = 0; mi < 4; mi++) {
#pragma unroll
        for (int ni = 0; ni < 4; ni++) {
#pragma unroll
            for (int e = 0; e < 4; e++) {
                const int rl = wr * 16 + q * 4 + e;
                const int col = wc * 64 + ni * 16 + r;
                St[rl * 136 + col] = f2bf(fmaxf(acc[mi][ni][e] + bv[ni], 0.f));
            }
        }
        __syncthreads();
        // readout: 512 chunks of 8 shorts (16B); each thread stores 2
#pragma unroll
        for (int j = 0; j < 2; j++) {
            const int id = t + 256 * j;
            const int rl = id >> 4;        // 0..31
            const int ch = id & 15;        // 0..15
            const int grow = m0 + (rl >> 4) * 64 + mi * 16 + (rl & 15);
            const short8_t v = *(const short8_t*)&St[rl * 136 + ch * 8];
            if (grow < M)
                *(short8_t*)&Y[(size_t)grow * DIM + n0 + ch * 8] = v;
        }
        __syncthreads();
    }
}

// ---------------- CSR build: histogram -> 3-phase scan -> fill ----------------
__global__ __launch_bounds__(256) void count_dst(
    const int* __restrict__ dst, int E, int* __restrict__ cnt)
{
    const int e = blockIdx.x * blockDim.x + threadIdx.x;
    if (e < E) atomicAdd(&cnt[dst[e]], 1);
}

// Phase 1: block b reduces cnt[b*1024 .. b*1024+1023] -> bsum[b].
// (R7: replaces the single-workgroup scan_counts -- 110 us at 0.14% occupancy,
//  pure one-CU latency walk. 3-phase scan spreads the 600 KB across the grid.)
__global__ __launch_bounds__(256) void scan_blocksums(
    const int* __restrict__ cnt, int N, int* __restrict__ bsum)
{
    __shared__ int red[256];
    const int t = threadIdx.x;
    const int base = blockIdx.x * 1024 + t * 4;
    int s = 0;
#pragma unroll
    for (int j = 0; j < 4; j++) {
        const int i = base + j;
        if (i < N) s += cnt[i];
    }
    red[t] = s;
    __syncthreads();
#pragma unroll
    for (int off = 128; off > 0; off >>= 1) {
        if (t < off) red[t] += red[t + off];
        __syncthreads();
    }
    if (t == 0) bsum[blockIdx.x] = red[0];
}

// Phase 2: single tiny block scans bsum[0..nb) (nb <= 64 for M < 65536)
// -> exclusive block offsets in-place; total -> rowptr[N].
__global__ __launch_bounds__(256) void scan_offsets(
    int* __restrict__ bsum, int nb, int* __restrict__ rowptr, int N)
{
    __shared__ int sh[256];
    const int t = threadIdx.x;
    sh[t] = (t < nb) ? bsum[t] : 0;
    __syncthreads();
    for (int off = 1; off < 256; off <<= 1) {
        const int add = (t >= off) ? sh[t - off] : 0;
        __syncthreads();
        sh[t] += add;
        __syncthreads();
    }
    if (t < nb) bsum[t] = (t == 0) ? 0 : sh[t - 1];
    if (t == 255) rowptr[N] = sh[255];
}

// Phase 3: block b rescans its 1024 cnts, adds bsum[b], writes rowptr+cursor.
__global__ __launch_bounds__(256) void scan_phase3(
    const int* __restrict__ cnt, int N, const int* __restrict__ bsum,
    int* __restrict__ rowptr, int* __restrict__ cursor)
{
    __shared__ int sh[256];
    const int t = threadIdx.x;
    const int base = blockIdx.x * 1024 + t * 4;
    int v[4];
#pragma unroll
    for (int j = 0; j < 4; j++) {
        const int i = base + j;
        v[j] = (i < N) ? cnt[i] : 0;
    }
    sh[t] = v[0] + v[1] + v[2] + v[3];
    __syncthreads();
    for (int off = 1; off < 256; off <<= 1) {
        const int add = (t >= off) ? sh[t - off] : 0;
        __syncthreads();
        sh[t] += add;
        __syncthreads();
    }
    int run = bsum[blockIdx.x] + ((t == 0) ? 0 : sh[t - 1]);
#pragma unroll
    for (int j = 0; j < 4; j++) {
        const int i = base + j;
        if (i < N) { rowptr[i] = run; cursor[i] = run; }
        run += v[j];
    }
}

__global__ __launch_bounds__(256) void fill_edges(
    const int* __restrict__ src, const int* __restrict__ dst,
    const int* __restrict__ et, int E, int* __restrict__ cursor,
    unsigned* __restrict__ ep)
{
    const int e = blockIdx.x * blockDim.x + threadIdx.x;
    if (e >= E) return;
    const int pos = atomicAdd(&cursor[dst[e]], 1);
    ep[pos] = (unsigned)src[e] | ((unsigned)et[e] << 16);
}

// -------- aggregate: gather + sum, 2 edges/wave, unroll x2 for MLP ---------
template <typename OT>
__global__ __launch_bounds__(256) void aggregate4(
    const unsigned short* __restrict__ yall,   // [R][M][256]
    const unsigned* __restrict__ ep, const int* __restrict__ rowptr,
    OT* __restrict__ out, int M)
{
    const int lane = threadIdx.x & 63;
    const int half = lane >> 5;     // which edge of a pair
    const int cl = lane & 31;       // 8-short chunk within message row
    const int wv = (blockIdx.x * blockDim.x + threadIdx.x) >> 6;
    const int nw = (gridDim.x * blockDim.x) >> 6;
    const size_t plane = (size_t)M * DIM;

    for (int d = wv; d < M; d += nw) {
        const int beg = rowptr[d], end = rowptr[d + 1];
        float acc[8];
#pragma unroll
        for (int j = 0; j < 8; j++) acc[j] = 0.f;

        for (int c0 = beg; c0 < end; c0 += 64) {
            const int n = min(64, end - c0);
            const unsigned myep = (c0 + lane < end) ? ep[c0 + lane] : 0u;
            // 4 edges per iteration: each half-wave issues 2 independent loads
            for (int i = 0; i < n; i += 4) {
                const int i0 = i + half;
                const int i1 = i + 2 + half;
                const unsigned p0 = __shfl(myep, i0 & 63);
                const unsigned p1 = __shfl(myep, i1 & 63);
                // loads always address-safe (myep==0 for OOB lanes)
                const short8_t u0 = *(const short8_t*)(
                    yall + (size_t)(p0 >> 16) * plane +
                    (size_t)(p0 & 0xFFFFu) * DIM + cl * 8);
                const short8_t u1 = *(const short8_t*)(
                    yall + (size_t)(p1 >> 16) * plane +
                    (size_t)(p1 & 0xFFFFu) * DIM + cl * 8);
                if (i0 < n) {
#pragma unroll
                    for (int j = 0; j < 8; j++)
                        acc[j] += bf2f((unsigned short)u0[j]);
                }
                if (i1 < n) {
#pragma unroll
                    for (int j = 0; j < 8; j++)
                        acc[j] += bf2f((unsigned short)u1[j]);
                }
            }
        }
        // fold the two halves: lane l (<32) adds lane l+32's accumulator
        float o[8];
#pragma unroll
        for (int j = 0; j < 8; j++)
            o[j] = acc[j] + __shfl(acc[j], (lane + 32) & 63);
        if (lane < 32) {
            OT* dp = out + (size_t)d * DIM + cl * 8;
            if (sizeof(OT) == 4) {
                *(float4*)((float*)dp) = make_float4(o[0], o[1], o[2], o[3]);
                *(float4*)((float*)dp + 4) = make_float4(o[4], o[5], o[6], o[7]);
            } else {
                short8_t v;
#pragma unroll
                for (int j = 0; j < 8; j++) v[j] = (short)f2bf(o[j]);
                *(short8_t*)((unsigned short*)dp) = v;
            }
        }
    }
}

// ---------------- fallback: fp32 vector GEMM + atomic scatter ----------------
__global__ __launch_bounds__(256) void gemm_bias_relu_f32(
    const float* __restrict__ A, const float* __restrict__ B,
    const float* __restrict__ bias, float* __restrict__ Y, int M)
{
    __shared__ float Asf[16][132];
    __shared__ float Bsf[16][128];
    const int t = threadIdx.x;
    const int tx = t & 15, ty = t >> 4;
    const int row0 = blockIdx.x * 128, col0 = blockIdx.y * 128;
    float acc[8][8];
#pragma unroll
    for (int i = 0; i < 8; i++)
#pragma unroll
        for (int j = 0; j < 8; j++) acc[i][j] = 0.f;
    const int arow = t >> 2, akseg = (t & 3) * 4;
    const int bk0 = t >> 5, bcol = (t & 31) * 4;
    for (int k0 = 0; k0 < DIM; k0 += 16) {
#pragma unroll
        for (int h = 0; h < 2; h++) {
            const int row = row0 + arow + h * 64;
            float4 av = (row < M) ? *(const float4*)(A + (size_t)row * DIM + k0 + akseg)
                                  : make_float4(0, 0, 0, 0);
            Asf[akseg + 0][arow + h * 64] = av.x;
            Asf[akseg + 1][arow + h * 64] = av.y;
            Asf[akseg + 2][arow + h * 64] = av.z;
            Asf[akseg + 3][arow + h * 64] = av.w;
        }
#pragma unroll
        for (int h = 0; h < 2; h++) {
            const int krow = bk0 + h * 8;
            *(float4*)&Bsf[krow][bcol] =
                *(const float4*)(B + (size_t)(k0 + krow) * DIM + col0 + bcol);
        }
        __syncthreads();
#pragma unroll
        for (int k = 0; k < 16; k++) {
            float a[8], b[8];
            *(float4*)&a[0] = *(const float4*)&Asf[k][ty * 4];
            *(float4*)&a[4] = *(const float4*)&Asf[k][64 + ty * 4];
            *(float4*)&b[0] = *(const float4*)&Bsf[k][tx * 4];
            *(float4*)&b[4] = *(const float4*)&Bsf[k][64 + tx * 4];
#pragma unroll
            for (int i = 0; i < 8; i++)
#pragma unroll
                for (int j = 0; j < 8; j++) acc[i][j] = fmaf(a[i], b[j], acc[i][j]);
        }
        __syncthreads();
    }
#pragma unroll
    for (int im = 0; im < 2; im++)
#pragma unroll
        for (int i = 0; i < 4; i++) {
            const int row = row0 + im * 64 + ty * 4 + i;
            if (row >= M) continue;
#pragma unroll
            for (int jm = 0; jm < 2; jm++) {
                const int col = col0 + jm * 64 + tx * 4;
                const float4 bb = *(const float4*)(bias + col);
                float4 o;
                o.x = fmaxf(acc[im * 4 + i][jm * 4 + 0] + bb.x, 0.f);
                o.y = fmaxf(acc[im * 4 + i][jm * 4 + 1] + bb.y, 0.f);
                o.z = fmaxf(acc[im * 4 + i][jm * 4 + 2] + bb.z, 0.f);
                o.w = fmaxf(acc[im * 4 + i][jm * 4 + 3] + bb.w, 0.f);
                *(float4*)(Y + (size_t)row * DIM + col) = o;
            }
        }
}

__global__ __launch_bounds__(256) void scatter_rel(
    const float* __restrict__ y, const int* __restrict__ src,
    const int* __restrict__ dst, const int* __restrict__ et,
    int rel, float* __restrict__ out, int n_edges)
{
    const int lane = threadIdx.x & 63;
    const int wave = (blockIdx.x * blockDim.x + threadIdx.x) >> 6;
    const int nwaves = (gridDim.x * blockDim.x) >> 6;
    for (int e = wave; e < n_edges; e += nwaves) {
        if (et[e] != rel) continue;
        const float4 v = *(const float4*)(y + (size_t)src[e] * DIM + lane * 4);
        float* o = out + (size_t)dst[e] * DIM + lane * 4;
        atomicAdd(o + 0, v.x);
        atomicAdd(o + 1, v.y);
        atomicAdd(o + 2, v.z);
        atomicAdd(o + 3, v.w);
    }
}

static inline size_t align16(size_t x) { return (x + 15) & ~(size_t)15; }

extern "C" void kernel_launch(void* const* d_in, const int* in_sizes, int n_in,
                              void* d_out, int out_size, void* d_ws, size_t ws_size,
                              hipStream_t stream)
{
    const float* x  = (const float*)d_in[0];
    const float* W0 = (const float*)d_in[1];
    const float* b0 = (const float*)d_in[2];
    const float* W1 = (const float*)d_in[3];
    const float* b1 = (const float*)d_in[4];
    const int* eidx = (const int*)d_in[5];
    const int* etyp = (const int*)d_in[6];

    const int M = in_sizes[0] / DIM;   // 50000
    const int E = in_sizes[6];         // 800000
    const int* src = eidx;
    const int* dst = eidx + E;
    float* out = (float*)d_out;

    const size_t plane = (size_t)M * DIM;
    const size_t wbytes = (size_t)N_REL * DIM * DIM * 2;

    const size_t need = align16(plane * 2)              // h1b
                      + align16(plane * 2)              // xb
                      + 2 * align16(wbytes)             // Wt0b, Wt1b
                      + align16((size_t)(M + 1) * 4)    // rowptr
                      + 2 * align16((size_t)M * 4)      // cnt, cursor
                      + align16((size_t)256 * 4)        // bsum (block sums)
                      + align16((size_t)E * 4)          // ep
                      + align16((size_t)N_REL * plane * 2);  // yall

    if (M < 65536 && ws_size >= need) {
        char* ws = (char*)d_ws;
        size_t off = 0;
        unsigned short* h1b  = (unsigned short*)(ws + off); off = align16(off + plane * 2);
        unsigned short* xb   = (unsigned short*)(ws + off); off = align16(off + plane * 2);
        unsigned short* Wt0b = (unsigned short*)(ws + off); off = align16(off + wbytes);
        unsigned short* Wt1b = (unsigned short*)(ws + off); off = align16(off + wbytes);
        int* rowptr = (int*)(ws + off); off = align16(off + (size_t)(M + 1) * 4);
        int* cnt    = (int*)(ws + off); off = align16(off + (size_t)M * 4);
        int* cursor = (int*)(ws + off); off = align16(off + (size_t)M * 4);
        int* bsum   = (int*)(ws + off); off = align16(off + (size_t)256 * 4);
        unsigned* ep = (unsigned*)(ws + off); off = align16(off + (size_t)E * 4);
        unsigned short* yall = (unsigned short*)(ws + off);

        // CSR build (shared by both layers). 3-phase parallel scan:
        // R7: the old single-workgroup scan_counts was 110 us (17% of total)
        // at 0.14% occupancy -- one CU walking 600 KB at memory latency.
        const int nb = (M + 1023) / 1024;   // <= 64 blocks for M < 65536
        hipMemsetAsync(cnt, 0, (size_t)M * 4, stream);
        count_dst<<<(E + 255) / 256, 256, 0, stream>>>(dst, E, cnt);
        scan_blocksums<<<nb, 256, 0, stream>>>(cnt, M, bsum);
        scan_offsets<<<1, 256, 0, stream>>>(bsum, nb, rowptr, M);
        scan_phase3<<<nb, 256, 0, stream>>>(cnt, M, bsum, rowptr, cursor);
        fill_edges<<<(E + 255) / 256, 256, 0, stream>>>(src, dst, etyp, E, cursor, ep);

        // prep: casts / transposes
        cast_f32_bf16<<<(int)((plane / 4 + 255) / 256), 256, 0, stream>>>(
            x, xb, (int)(plane / 4));
        transpose_cast_w<<<dim3(8, 8, N_REL), dim3(32, 8), 0, stream>>>(W0, Wt0b);
        transpose_cast_w<<<dim3(8, 8, N_REL), dim3(32, 8), 0, stream>>>(W1, Wt1b);

        const int Rtiles = (M + 127) / 128;
        const int octets = (Rtiles + 7) / 8;
        const int ggrid = octets * 16 * 8;
        const int agrid = (int)(((size_t)M * 64 + 255) / 256); // 1 wave/dst

        // layer 1
        gemm_mfma_bias_relu<<<ggrid, 256, 0, stream>>>(xb, Wt0b, b0, yall, M, Rtiles);
        aggregate4<unsigned short><<<agrid, 256, 0, stream>>>(yall, ep, rowptr, h1b, M);
        // layer 2
        gemm_mfma_bias_relu<<<ggrid, 256, 0, stream>>>(h1b, Wt1b, b1, yall, M, Rtiles);
        aggregate4<float><<<agrid, 256, 0, stream>>>(yall, ep, rowptr, out, M);
    } else {
        // fallback: fp32 per-relation GEMM + atomic scatter
        float* h1 = (float*)d_ws;
        float* y  = (float*)d_ws + plane;
        const dim3 gblk(256), ggrid2((M + 127) / 128, DIM / 128);
        hipMemsetAsync(h1, 0, plane * 4, stream);
        for (int r = 0; r < N_REL; r++) {
            gemm_bias_relu_f32<<<ggrid2, gblk, 0, stream>>>(
                x, W0 + (size_t)r * DIM * DIM, b0, y, M);
            scatter_rel<<<1024, 256, 0, stream>>>(y, src, dst, etyp, r, h1, E);
        }
        hipMemsetAsync(out, 0, plane * 4, stream);
        for (int r = 0; r < N_REL; r++) {
            gemm_bias_relu_f32<<<ggrid2, gblk, 0, stream>>>(
                h1, W1 + (size_t)r * DIM * DIM, b1, y, M);
            scatter_rel<<<1024, 256, 0, stream>>>(y, src, dst, etyp, r, out, E);
        }
    }
}

// Round 3
// 508.746 us; speedup vs baseline: 1.2783x; 1.0024x over previous
//
#include <hip/hip_runtime.h>

#define DIM 256
#define N_REL 8

typedef __attribute__((ext_vector_type(8))) short short8_t;
typedef __attribute__((ext_vector_type(4))) float float4_t;

// ---------------- bf16 helpers (manual, RNE) ----------------
__device__ inline unsigned short f2bf(float f) {
    unsigned u = __float_as_uint(f);
    u += 0x7FFFu + ((u >> 16) & 1u);
    return (unsigned short)(u >> 16);
}
__device__ inline float bf2f(unsigned short h) {
    return __uint_as_float(((unsigned)h) << 16);
}

// ---------------- cast / transpose prep kernels ----------------
__global__ __launch_bounds__(256) void cast_f32_bf16(
    const float* __restrict__ in, unsigned short* __restrict__ out, int n4)
{
    const int i = blockIdx.x * blockDim.x + threadIdx.x;
    if (i >= n4) return;
    const float4 v = ((const float4*)in)[i];
    ushort4 o;
    o.x = f2bf(v.x); o.y = f2bf(v.y); o.z = f2bf(v.z); o.w = f2bf(v.w);
    ((ushort4*)out)[i] = o;
}

// W[rel][in][out] f32  ->  Wt[rel][out][in] bf16
__global__ __launch_bounds__(256) void transpose_cast_w(
    const float* __restrict__ W, unsigned short* __restrict__ Wt)
{
    __shared__ float tile[32][33];
    const int rel = blockIdx.z;
    const int i0 = blockIdx.x * 32, o0 = blockIdx.y * 32;
    const int tx = threadIdx.x, ty = threadIdx.y;   // (32, 8)
    const float* Wr = W + (size_t)rel * DIM * DIM;
    unsigned short* Wtr = Wt + (size_t)rel * DIM * DIM;
#pragma unroll
    for (int j = 0; j < 4; j++)
        tile[ty + 8 * j][tx] = Wr[(size_t)(i0 + ty + 8 * j) * DIM + o0 + tx];
    __syncthreads();
#pragma unroll
    for (int j = 0; j < 4; j++)
        Wtr[(size_t)(o0 + ty + 8 * j) * DIM + i0 + tx] = f2bf(tile[tx][ty + 8 * j]);
}

// ---------------------------------------------------------------------------
// Yall[rel][M][256] = relu(Xb @ W[rel] + bias) in bf16.
// Tile 128x128, BK=32, 4 waves of 64x64 (4x4 mfma_f32_16x16x32_bf16).
// R8: global_load_lds width=16 (HBM->LDS DMA), XOR seg swizzle applied BOTH
// to global source and ds_read offset (rule 21) -> conflicts 1.36e7->8e5.
// R9: 3-buffer / 2-step-lookahead pipeline. R8's 1-deep prefetch left a
// ~500cy HBM-latency residual at every vmcnt(4): one K-step of MFMA (~400cy)
// can't cover ~900cy HBM latency. Now STAGE(ks+2) is issued each step and
// vmcnt(8) keeps 2 tiles (8 loads/wave) in flight. LDS 48KB -> 3 blocks/CU.
// K-loop fully unrolled so buffer offsets are static (rule #20).
// Epilogue: 2 mi-blocks per LDS round (64x136) -> 4 syncthreads not 8, and
// 4 independent 16B stores/thread.
// OOB A-rows of the last tile load garbage (in-workspace) but those acc rows
// are never stored (grow<M guard).
// 1-D grid, octet swizzle: rt = (L>>7)*8 | (L&7) pins each row-tile to one
// XCD across all 16 (ntile, rel) combos -> A fetched ~once (FETCH 17.6MB).
// NOTE: epilogue mi-loop MUST be fully unrolled: a runtime index into acc[]
// demotes the accumulator to scratch (R4/R5: 3.7 GB WRITE_SIZE, VGPR 88->64).
// ---------------------------------------------------------------------------
__global__ __launch_bounds__(256) void gemm_mfma_bias_relu(
    const unsigned short* __restrict__ Xb,    // [M][256]
    const unsigned short* __restrict__ Wtb,   // [R][256out][256in]
    const float* __restrict__ bias,           // [256]
    unsigned short* __restrict__ Yall, int M, int Rtiles)
{
    // 3 buffers of 8192 shorts: buf b = smem + b*8192 (As 4096 | Bs 4096)
    __shared__ __align__(16) short smem[24576];   // 48 KiB

    const unsigned L = blockIdx.x;
    const int xcd = L & 7;
    const unsigned g = L >> 3;
    const int combo = g & 15;                 // (ntile, rel)
    const int rt = (int)((g >> 4) << 3) | xcd;
    if (rt >= Rtiles) return;
    const int m0 = rt * 128;
    const int n0 = (combo & 1) * 128;
    const int rel = combo >> 1;

    const unsigned short* Wt = Wtb + (size_t)rel * DIM * DIM;
    unsigned short* Y = Yall + (size_t)rel * M * DIM;

    const int t = threadIdx.x;
    const int lane = t & 63;
    const int w = t >> 6;
    const int wr = w & 1, wc = w >> 1;
    const int r = lane & 15, q = lane >> 4;

    // ---- staging geometry: chunk c = h*256 + w*64 + lane, c=(row*4+slot) ----
    const int sl = lane & 3;            // 16B slot within 64B row
    const int rsub = lane >> 2;         // 0..15
    const unsigned short* gA[2];
    const unsigned short* gB[2];
#pragma unroll
    for (int h = 0; h < 2; h++) {
        const int row = h * 64 + w * 16 + rsub;          // 0..127
        const int gseg = sl ^ ((row >> 1) & 3);          // pre-swizzled source
        gA[h] = Xb + (size_t)(m0 + row) * DIM + gseg * 8;
        gB[h] = Wt + (size_t)(n0 + row) * DIM + gseg * 8;
    }

    // ---- fragment read offsets (shorts), constant across K-steps ----
    const int swz = (q ^ ((r >> 1) & 3)) * 8;            // swizzled k-segment
    int offA[4], offB[4];
#pragma unroll
    for (int mi = 0; mi < 4; mi++)
        offA[mi] = (wr * 64 + mi * 16 + r) * 32 + swz;
#pragma unroll
    for (int ni = 0; ni < 4; ni++)
        offB[ni] = (wc * 64 + ni * 16 + r) * 32 + swz;

    float4_t acc[4][4];
#pragma unroll
    for (int i = 0; i < 4; i++)
#pragma unroll
        for (int j = 0; j < 4; j++) {
            float4_t z = {0.f, 0.f, 0.f, 0.f};
            acc[i][j] = z;
        }

    // 4 global_load_lds per wave per K-step (2 A + 2 B), each 16B/lane.
#define STAGE(ks, bsel)                                                         \
    {                                                                           \
        const int k0_ = (ks) * 32;                                              \
        short* Ad_ = smem + (bsel) * 8192;                                      \
        short* Bd_ = Ad_ + 4096;                                                \
        _Pragma("unroll")                                                       \
        for (int h = 0; h < 2; h++) {                                           \
            __builtin_amdgcn_global_load_lds(                                   \
                (const __attribute__((address_space(1))) unsigned int*)(gA[h] + k0_), \
                (__attribute__((address_space(3))) unsigned int*)(Ad_ + h * 2048 + w * 512), \
                16, 0, 0);                                                      \
            __builtin_amdgcn_global_load_lds(                                   \
                (const __attribute__((address_space(1))) unsigned int*)(gB[h] + k0_), \
                (__attribute__((address_space(3))) unsigned int*)(Bd_ + h * 2048 + w * 512), \
                16, 0, 0);                                                      \
        }                                                                       \
    }

    STAGE(0, 0);
    STAGE(1, 1);
#pragma unroll
    for (int ks = 0; ks < 8; ks++) {
        if (ks < 6) {
            STAGE(ks + 2, (ks + 2) % 3);
            // 2 tiles (8 loads) stay in flight across the barrier
            asm volatile("s_waitcnt vmcnt(8)" ::: "memory");
        } else if (ks == 6) {
            asm volatile("s_waitcnt vmcnt(4)" ::: "memory");
        } else {
            asm volatile("s_waitcnt vmcnt(0)" ::: "memory");
        }
        asm volatile("s_barrier" ::: "memory");

        const short* As_b = smem + (ks % 3) * 8192;
        const short* Bs_b = As_b + 4096;
        short8_t af[4], bf[4];
#pragma unroll
        for (int mi = 0; mi < 4; mi++)
            af[mi] = *(const short8_t*)&As_b[offA[mi]];
#pragma unroll
        for (int ni = 0; ni < 4; ni++)
            bf[ni] = *(const short8_t*)&Bs_b[offB[ni]];
#pragma unroll
        for (int mi = 0; mi < 4; mi++)
#pragma unroll
            for (int ni = 0; ni < 4; ni++)
                acc[mi][ni] = __builtin_amdgcn_mfma_f32_16x16x32_bf16(
                    af[mi], bf[ni], acc[mi][ni], 0, 0, 0);
        asm volatile("s_barrier" ::: "memory");
    }
#undef STAGE

    // ---- epilogue: bias+relu, LDS-staged coalesced bf16 stores (2 rounds) ----
    short* St = smem;   // 64*136 = 8704 shorts, aliases buffers (K-loop done)

    float bv[4];
#pragma unroll
    for (int ni = 0; ni < 4; ni++)
        bv[ni] = bias[n0 + wc * 64 + ni * 16 + r];

#pragma unroll
    for (int mp = 0; mp < 2; mp++) {
#pragma unroll
        for (int s = 0; s < 2; s++) {
#pragma unroll
            for (int ni = 0; ni < 4; ni++) {
#pragma unroll
                for (int e = 0; e < 4; e++) {
                    const int rl = s * 32 + wr * 16 + q * 4 + e;
                    const int col = wc * 64 + ni * 16 + r;
                    St[rl * 136 + col] =
                        f2bf(fmaxf(acc[mp * 2 + s][ni][e] + bv[ni], 0.f));
                }
            }
        }
        __syncthreads();
        // readout: 1024 chunks of 8 shorts (16B); each thread stores 4
#pragma unroll
        for (int j = 0; j < 4; j++) {
            const int id = t + 256 * j;
            const int rl2 = id >> 4;       // 0..63
            const int ch = id & 15;        // 0..15
            const int s = rl2 >> 5;
            const int rl = rl2 & 31;
            const int grow = m0 + (rl >> 4) * 64 + (mp * 2 + s) * 16 + (rl & 15);
            const short8_t v = *(const short8_t*)&St[rl2 * 136 + ch * 8];
            if (grow < M)
                *(short8_t*)&Y[(size_t)grow * DIM + n0 + ch * 8] = v;
        }
        if (mp == 0) __syncthreads();
    }
}

// ---------------- CSR build: histogram -> 3-phase scan -> fill ----------------
__global__ __launch_bounds__(256) void count_dst(
    const int* __restrict__ dst, int E, int* __restrict__ cnt)
{
    const int e = blockIdx.x * blockDim.x + threadIdx.x;
    if (e < E) atomicAdd(&cnt[dst[e]], 1);
}

// Phase 1: block b reduces cnt[b*1024 .. b*1024+1023] -> bsum[b].
// (R7: replaces the single-workgroup scan_counts -- 110 us at 0.14% occupancy,
//  pure one-CU latency walk. 3-phase scan spreads the 600 KB across the grid.)
__global__ __launch_bounds__(256) void scan_blocksums(
    const int* __restrict__ cnt, int N, int* __restrict__ bsum)
{
    __shared__ int red[256];
    const int t = threadIdx.x;
    const int base = blockIdx.x * 1024 + t * 4;
    int s = 0;
#pragma unroll
    for (int j = 0; j < 4; j++) {
        const int i = base + j;
        if (i < N) s += cnt[i];
    }
    red[t] = s;
    __syncthreads();
#pragma unroll
    for (int off = 128; off > 0; off >>= 1) {
        if (t < off) red[t] += red[t + off];
        __syncthreads();
    }
    if (t == 0) bsum[blockIdx.x] = red[0];
}

// Phase 2: single tiny block scans bsum[0..nb) (nb <= 64 for M < 65536)
// -> exclusive block offsets in-place; total -> rowptr[N].
__global__ __launch_bounds__(256) void scan_offsets(
    int* __restrict__ bsum, int nb, int* __restrict__ rowptr, int N)
{
    __shared__ int sh[256];
    const int t = threadIdx.x;
    sh[t] = (t < nb) ? bsum[t] : 0;
    __syncthreads();
    for (int off = 1; off < 256; off <<= 1) {
        const int add = (t >= off) ? sh[t - off] : 0;
        __syncthreads();
        sh[t] += add;
        __syncthreads();
    }
    if (t < nb) bsum[t] = (t == 0) ? 0 : sh[t - 1];
    if (t == 255) rowptr[N] = sh[255];
}

// Phase 3: block b rescans its 1024 cnts, adds bsum[b], writes rowptr+cursor.
__global__ __launch_bounds__(256) void scan_phase3(
    const int* __restrict__ cnt, int N, const int* __restrict__ bsum,
    int* __restrict__ rowptr, int* __restrict__ cursor)
{
    __shared__ int sh[256];
    const int t = threadIdx.x;
    const int base = blockIdx.x * 1024 + t * 4;
    int v[4];
#pragma unroll
    for (int j = 0; j < 4; j++) {
        const int i = base + j;
        v[j] = (i < N) ? cnt[i] : 0;
    }
    sh[t] = v[0] + v[1] + v[2] + v[3];
    __syncthreads();
    for (int off = 1; off < 256; off <<= 1) {
        const int add = (t >= off) ? sh[t - off] : 0;
        __syncthreads();
        sh[t] += add;
        __syncthreads();
    }
    int run = bsum[blockIdx.x] + ((t == 0) ? 0 : sh[t - 1]);
#pragma unroll
    for (int j = 0; j < 4; j++) {
        const int i = base + j;
        if (i < N) { rowptr[i] = run; cursor[i] = run; }
        run += v[j];
    }
}

__global__ __launch_bounds__(256) void fill_edges(
    const int* __restrict__ src, const int* __restrict__ dst,
    const int* __restrict__ et, int E, int* __restrict__ cursor,
    unsigned* __restrict__ ep)
{
    const int e = blockIdx.x * blockDim.x + threadIdx.x;
    if (e >= E) return;
    const int pos = atomicAdd(&cursor[dst[e]], 1);
    ep[pos] = (unsigned)src[e] | ((unsigned)et[e] << 16);
}

// -------- aggregate: gather + sum, 8 edges/iter, 4 loads in flight ---------
// R9: R8 version had only 2 gathers in flight per half-wave -> 47% HBM,
// latency-bound (VGPR 20, VALUBusy 24%). Now each half-wave issues 4
// independent 512B-row gathers before the first accumulate.
template <typename OT>
__global__ __launch_bounds__(256) void aggregate4(
    const unsigned short* __restrict__ yall,   // [R][M][256]
    const unsigned* __restrict__ ep, const int* __restrict__ rowptr,
    OT* __restrict__ out, int M)
{
    const int lane = threadIdx.x & 63;
    const int half = lane >> 5;     // which edge of a pair
    const int cl = lane & 31;       // 8-short chunk within message row
    const int wv = (blockIdx.x * blockDim.x + threadIdx.x) >> 6;
    const int nw = (gridDim.x * blockDim.x) >> 6;
    const size_t plane = (size_t)M * DIM;

    for (int d = wv; d < M; d += nw) {
        const int beg = rowptr[d], end = rowptr[d + 1];
        float acc[8];
#pragma unroll
        for (int j = 0; j < 8; j++) acc[j] = 0.f;

        for (int c0 = beg; c0 < end; c0 += 64) {
            const int n = min(64, end - c0);
            const unsigned myep = (c0 + lane < end) ? ep[c0 + lane] : 0u;
            // 8 edges per iteration: each half-wave has 4 loads in flight
            for (int i = 0; i < n; i += 8) {
                short8_t u[4];
#pragma unroll
                for (int j = 0; j < 4; j++) {
                    const unsigned p = __shfl(myep, (i + 2 * j + half) & 63);
                    // loads always address-safe (myep==0 for OOB lanes)
                    u[j] = *(const short8_t*)(
                        yall + (size_t)(p >> 16) * plane +
                        (size_t)(p & 0xFFFFu) * DIM + cl * 8);
                }
#pragma unroll
                for (int j = 0; j < 4; j++) {
                    if (i + 2 * j + half < n) {
#pragma unroll
                        for (int k = 0; k < 8; k++)
                            acc[k] += bf2f((unsigned short)u[j][k]);
                    }
                }
            }
        }
        // fold the two halves: lane l (<32) adds lane l+32's accumulator
        float o[8];
#pragma unroll
        for (int j = 0; j < 8; j++)
            o[j] = acc[j] + __shfl(acc[j], (lane + 32) & 63);
        if (lane < 32) {
            OT* dp = out + (size_t)d * DIM + cl * 8;
            if (sizeof(OT) == 4) {
                *(float4*)((float*)dp) = make_float4(o[0], o[1], o[2], o[3]);
                *(float4*)((float*)dp + 4) = make_float4(o[4], o[5], o[6], o[7]);
            } else {
                short8_t v;
#pragma unroll
                for (int j = 0; j < 8; j++) v[j] = (short)f2bf(o[j]);
                *(short8_t*)((unsigned short*)dp) = v;
            }
        }
    }
}

// ---------------- fallback: fp32 vector GEMM + atomic scatter ----------------
__global__ __launch_bounds__(256) void gemm_bias_relu_f32(
    const float* __restrict__ A, const float* __restrict__ B,
    const float* __restrict__ bias, float* __restrict__ Y, int M)
{
    __shared__ float Asf[16][132];
    __shared__ float Bsf[16][128];
    const int t = threadIdx.x;
    const int tx = t & 15, ty = t >> 4;
    const int row0 = blockIdx.x * 128, col0 = blockIdx.y * 128;
    float acc[8][8];
#pragma unroll
    for (int i = 0; i < 8; i++)
#pragma unroll
        for (int j = 0; j < 8; j++) acc[i][j] = 0.f;
    const int arow = t >> 2, akseg = (t & 3) * 4;
    const int bk0 = t >> 5, bcol = (t & 31) * 4;
    for (int k0 = 0; k0 < DIM; k0 += 16) {
#pragma unroll
        for (int h = 0; h < 2; h++) {
            const int row = row0 + arow + h * 64;
            float4 av = (row < M) ? *(const float4*)(A + (size_t)row * DIM + k0 + akseg)
                                  : make_float4(0, 0, 0, 0);
            Asf[akseg + 0][arow + h * 64] = av.x;
            Asf[akseg + 1][arow + h * 64] = av.y;
            Asf[akseg + 2][arow + h * 64] = av.z;
            Asf[akseg + 3][arow + h * 64] = av.w;
        }
#pragma unroll
        for (int h = 0; h < 2; h++) {
            const int krow = bk0 + h * 8;
            *(float4*)&Bsf[krow][bcol] =
                *(const float4*)(B + (size_t)(k0 + krow) * DIM + col0 + bcol);
        }
        __syncthreads();
#pragma unroll
        for (int k = 0; k < 16; k++) {
            float a[8], b[8];
            *(float4*)&a[0] = *(const float4*)&Asf[k][ty * 4];
            *(float4*)&a[4] = *(const float4*)&Asf[k][64 + ty * 4];
            *(float4*)&b[0] = *(const float4*)&Bsf[k][tx * 4];
            *(float4*)&b[4] = *(const float4*)&Bsf[k][64 + tx * 4];
#pragma unroll
            for (int i = 0; i < 8; i++)
#pragma unroll
                for (int j = 0; j < 8; j++) acc[i][j] = fmaf(a[i], b[j], acc[i][j]);
        }
        __syncthreads();
    }
#pragma unroll
    for (int im = 0; im < 2; im++)
#pragma unroll
        for (int i = 0; i < 4; i++) {
            const int row = row0 + im * 64 + ty * 4 + i;
            if (row >= M) continue;
#pragma unroll
            for (int jm = 0; jm < 2; jm++) {
                const int col = col0 + jm * 64 + tx * 4;
                const float4 bb = *(const float4*)(bias + col);
                float4 o;
                o.x = fmaxf(acc[im * 4 + i][jm * 4 + 0] + bb.x, 0.f);
                o.y = fmaxf(acc[im * 4 + i][jm * 4 + 1] + bb.y, 0.f);
                o.z = fmaxf(acc[im * 4 + i][jm * 4 + 2] + bb.z, 0.f);
                o.w = fmaxf(acc[im * 4 + i][jm * 4 + 3] + bb.w, 0.f);
                *(float4*)(Y + (size_t)row * DIM + col) = o;
            }
        }
}

__global__ __launch_bounds__(256) void scatter_rel(
    const float* __restrict__ y, const int* __restrict__ src,
    const int* __restrict__ dst, const int* __restrict__ et,
    int rel, float* __restrict__ out, int n_edges)
{
    const int lane = threadIdx.x & 63;
    const int wave = (blockIdx.x * blockDim.x + threadIdx.x) >> 6;
    const int nwaves = (gridDim.x * blockDim.x) >> 6;
    for (int e = wave; e < n_edges; e += nwaves) {
        if (et[e] != rel) continue;
        const float4 v = *(const float4*)(y + (size_t)src[e] * DIM + lane * 4);
        float* o = out + (size_t)dst[e] * DIM + lane * 4;
        atomicAdd(o + 0, v.x);
        atomicAdd(o + 1, v.y);
        atomicAdd(o + 2, v.z);
        atomicAdd(o + 3, v.w);
    }
}

static inline size_t align16(size_t x) { return (x + 15) & ~(size_t)15; }

extern "C" void kernel_launch(void* const* d_in, const int* in_sizes, int n_in,
                              void* d_out, int out_size, void* d_ws, size_t ws_size,
                              hipStream_t stream)
{
    const float* x  = (const float*)d_in[0];
    const float* W0 = (const float*)d_in[1];
    const float* b0 = (const float*)d_in[2];
    const float* W1 = (const float*)d_in[3];
    const float* b1 = (const float*)d_in[4];
    const int* eidx = (const int*)d_in[5];
    const int* etyp = (const int*)d_in[6];

    const int M = in_sizes[0] / DIM;   // 50000
    const int E = in_sizes[6];         // 800000
    const int* src = eidx;
    const int* dst = eidx + E;
    float* out = (float*)d_out;

    const size_t plane = (size_t)M * DIM;
    const size_t wbytes = (size_t)N_REL * DIM * DIM * 2;

    const size_t need = align16(plane * 2)              // h1b
                      + align16(plane * 2)              // xb
                      + 2 * align16(wbytes)             // Wt0b, Wt1b
                      + align16((size_t)(M + 1) * 4)    // rowptr
                      + 2 * align16((size_t)M * 4)      // cnt, cursor
                      + align16((size_t)256 * 4)        // bsum (block sums)
                      + align16((size_t)E * 4)          // ep
                      + align16((size_t)N_REL * plane * 2);  // yall

    if (M < 65536 && ws_size >= need) {
        char* ws = (char*)d_ws;
        size_t off = 0;
        unsigned short* h1b  = (unsigned short*)(ws + off); off = align16(off + plane * 2);
        unsigned short* xb   = (unsigned short*)(ws + off); off = align16(off + plane * 2);
        unsigned short* Wt0b = (unsigned short*)(ws + off); off = align16(off + wbytes);
        unsigned short* Wt1b = (unsigned short*)(ws + off); off = align16(off + wbytes);
        int* rowptr = (int*)(ws + off); off = align16(off + (size_t)(M + 1) * 4);
        int* cnt    = (int*)(ws + off); off = align16(off + (size_t)M * 4);
        int* cursor = (int*)(ws + off); off = align16(off + (size_t)M * 4);
        int* bsum   = (int*)(ws + off); off = align16(off + (size_t)256 * 4);
        unsigned* ep = (unsigned*)(ws + off); off = align16(off + (size_t)E * 4);
        unsigned short* yall = (unsigned short*)(ws + off);

        // CSR build (shared by both layers). 3-phase parallel scan:
        // R7: the old single-workgroup scan_counts was 110 us (17% of total)
        // at 0.14% occupancy -- one CU walking 600 KB at memory latency.
        const int nb = (M + 1023) / 1024;   // <= 64 blocks for M < 65536
        hipMemsetAsync(cnt, 0, (size_t)M * 4, stream);
        count_dst<<<(E + 255) / 256, 256, 0, stream>>>(dst, E, cnt);
        scan_blocksums<<<nb, 256, 0, stream>>>(cnt, M, bsum);
        scan_offsets<<<1, 256, 0, stream>>>(bsum, nb, rowptr, M);
        scan_phase3<<<nb, 256, 0, stream>>>(cnt, M, bsum, rowptr, cursor);
        fill_edges<<<(E + 255) / 256, 256, 0, stream>>>(src, dst, etyp, E, cursor, ep);

        // prep: casts / transposes
        cast_f32_bf16<<<(int)((plane / 4 + 255) / 256), 256, 0, stream>>>(
            x, xb, (int)(plane / 4));
        transpose_cast_w<<<dim3(8, 8, N_REL), dim3(32, 8), 0, stream>>>(W0, Wt0b);
        transpose_cast_w<<<dim3(8, 8, N_REL), dim3(32, 8), 0, stream>>>(W1, Wt1b);

        const int Rtiles = (M + 127) / 128;
        const int octets = (Rtiles + 7) / 8;
        const int ggrid = octets * 16 * 8;
        const int agrid = (int)(((size_t)M * 64 + 255) / 256); // 1 wave/dst

        // layer 1
        gemm_mfma_bias_relu<<<ggrid, 256, 0, stream>>>(xb, Wt0b, b0, yall, M, Rtiles);
        aggregate4<unsigned short><<<agrid, 256, 0, stream>>>(yall, ep, rowptr, h1b, M);
        // layer 2
        gemm_mfma_bias_relu<<<ggrid, 256, 0, stream>>>(h1b, Wt1b, b1, yall, M, Rtiles);
        aggregate4<float><<<agrid, 256, 0, stream>>>(yall, ep, rowptr, out, M);
    } else {
        // fallback: fp32 per-relation GEMM + atomic scatter
        float* h1 = (float*)d_ws;
        float* y  = (float*)d_ws + plane;
        const dim3 gblk(256), ggrid2((M + 127) / 128, DIM / 128);
        hipMemsetAsync(h1, 0, plane * 4, stream);
        for (int r = 0; r < N_REL; r++) {
            gemm_bias_relu_f32<<<ggrid2, gblk, 0, stream>>>(
                x, W0 + (size_t)r * DIM * DIM, b0, y, M);
            scatter_rel<<<1024, 256, 0, stream>>>(y, src, dst, etyp, r, h1, E);
        }
        hipMemsetAsync(out, 0, plane * 4, stream);
        for (int r = 0; r < N_REL; r++) {
            gemm_bias_relu_f32<<<ggrid2, gblk, 0, stream>>>(
                h1, W1 + (size_t)r * DIM * DIM, b1, y, M);
            scatter_rel<<<1024, 256, 0, stream>>>(y, src, dst, etyp, r, out, E);
        }
    }
}

// Round 5
// 497.411 us; speedup vs baseline: 1.3074x; 1.0228x over previous
//
#include <hip/hip_runtime.h>

#define DIM 256
#define N_REL 8

typedef __attribute__((ext_vector_type(8))) short short8_t;
typedef __attribute__((ext_vector_type(4))) float float4_t;

// ---------------- bf16 helpers (manual, RNE) ----------------
__device__ inline unsigned short f2bf(float f) {
    unsigned u = __float_as_uint(f);
    u += 0x7FFFu + ((u >> 16) & 1u);
    return (unsigned short)(u >> 16);
}
__device__ inline float bf2f(unsigned short h) {
    return __uint_as_float(((unsigned)h) << 16);
}

// ---------------------------------------------------------------------------
// R10 prep megakernel: {cast x->bf16 | transpose W0 | transpose W1 | count_dst}
// fused into one dispatch (all independent).
// Block ranges: [0,nCast) cast, [nCast,nCast+512) W0, [+512,+1024) W1,
// rest count_dst.
// ---------------------------------------------------------------------------
__global__ __launch_bounds__(256) void prep_mega(
    const float* __restrict__ x, unsigned short* __restrict__ xb, int n4,
    const float* __restrict__ W0, unsigned short* __restrict__ Wt0,
    const float* __restrict__ W1, unsigned short* __restrict__ Wt1,
    const int* __restrict__ dst, int E, int* __restrict__ cnt,
    int nCast, int nW)
{
    __shared__ float tile[32][33];
    const int b = blockIdx.x;
    const int t = threadIdx.x;
    if (b < nCast) {
        const int i = b * 256 + t;
        if (i < n4) {
            const float4 v = ((const float4*)x)[i];
            ushort4 o;
            o.x = f2bf(v.x); o.y = f2bf(v.y); o.z = f2bf(v.z); o.w = f2bf(v.w);
            ((ushort4*)xb)[i] = o;
        }
    } else if (b < nCast + 2 * nW) {
        const int wi = b - nCast;
        const float* W = (wi < nW) ? W0 : W1;
        unsigned short* Wt = (wi < nW) ? Wt0 : Wt1;
        const int bb = (wi < nW) ? wi : wi - nW;
        const int rel = bb >> 6;
        const int bx = bb & 7, by = (bb >> 3) & 7;
        const int i0 = bx * 32, o0 = by * 32;
        const int tx = t & 31, ty = t >> 5;          // (32, 8)
        const float* Wr = W + (size_t)rel * DIM * DIM;
        unsigned short* Wtr = Wt + (size_t)rel * DIM * DIM;
#pragma unroll
        for (int j = 0; j < 4; j++)
            tile[ty + 8 * j][tx] = Wr[(size_t)(i0 + ty + 8 * j) * DIM + o0 + tx];
        __syncthreads();
#pragma unroll
        for (int j = 0; j < 4; j++)
            Wtr[(size_t)(o0 + ty + 8 * j) * DIM + i0 + tx] =
                f2bf(tile[tx][ty + 8 * j]);
    } else {
        const int e = (b - nCast - 2 * nW) * 256 + t;
        if (e < E) atomicAdd(&cnt[dst[e]], 1);
    }
}

// ---------------------------------------------------------------------------
// Yall[rel][M][256] = relu(Xb @ W[rel] + bias) in bf16.
// Tile 128x128, BK=32, 4 waves of 64x64 (4x4 mfma_f32_16x16x32_bf16).
// R8: global_load_lds width=16 (HBM->LDS DMA), XOR seg swizzle applied BOTH
// to global source and ds_read offset (rule 21) -> conflicts 1.36e7->8e5.
// R11: REVERTED R9's 3-buffer/vmcnt(8) pipeline back to R8's 2-buffer
// vmcnt(4) schedule: R9 was perf-neutral (implicit multi-block wave overlap
// already hides HBM latency at 3 blocks/CU) and correlated with the absmax
// jump 1.0->5.5; the verified R8 schedule (absmax 1.0, 81us) is restored.
// Kept R9's 2-round epilogue (bitwise-identical mapping, fewer barriers).
// OOB A-rows of the last tile load garbage (in-workspace) but those acc rows
// are never stored (grow<M guard).
// 1-D grid, octet swizzle: rt = (L>>7)*8 | (L&7) pins each row-tile to one
// XCD across all 16 (ntile, rel) combos -> A fetched ~once (FETCH 17.6MB).
// NOTE: epilogue mi-loop MUST be fully unrolled: a runtime index into acc[]
// demotes the accumulator to scratch (R4/R5: 3.7 GB WRITE_SIZE, VGPR 88->64).
// ---------------------------------------------------------------------------
__global__ __launch_bounds__(256) void gemm_mfma_bias_relu(
    const unsigned short* __restrict__ Xb,    // [M][256]
    const unsigned short* __restrict__ Wtb,   // [R][256out][256in]
    const float* __restrict__ bias,           // [256]
    unsigned short* __restrict__ Yall, int M, int Rtiles)
{
    // buf0: As 0..4095 | Bs 4096..8191 ; buf1: As 8192.. | Bs 12288.. (shorts)
    __shared__ __align__(16) short smem[16384];   // 32 KiB

    const unsigned L = blockIdx.x;
    const int xcd = L & 7;
    const unsigned g = L >> 3;
    const int combo = g & 15;                 // (ntile, rel)
    const int rt = (int)((g >> 4) << 3) | xcd;
    if (rt >= Rtiles) return;
    const int m0 = rt * 128;
    const int n0 = (combo & 1) * 128;
    const int rel = combo >> 1;

    const unsigned short* Wt = Wtb + (size_t)rel * DIM * DIM;
    unsigned short* Y = Yall + (size_t)rel * M * DIM;

    const int t = threadIdx.x;
    const int lane = t & 63;
    const int w = t >> 6;
    const int wr = w & 1, wc = w >> 1;
    const int r = lane & 15, q = lane >> 4;

    // ---- staging geometry: chunk c = h*256 + w*64 + lane, c=(row*4+slot) ----
    const int sl = lane & 3;            // 16B slot within 64B row
    const int rsub = lane >> 2;         // 0..15
    const unsigned short* gA[2];
    const unsigned short* gB[2];
#pragma unroll
    for (int h = 0; h < 2; h++) {
        const int row = h * 64 + w * 16 + rsub;          // 0..127
        const int gseg = sl ^ ((row >> 1) & 3);          // pre-swizzled source
        gA[h] = Xb + (size_t)(m0 + row) * DIM + gseg * 8;
        gB[h] = Wt + (size_t)(n0 + row) * DIM + gseg * 8;
    }

    // ---- fragment read offsets (shorts), constant across K-steps ----
    const int swz = (q ^ ((r >> 1) & 3)) * 8;            // swizzled k-segment
    int offA[4], offB[4];
#pragma unroll
    for (int mi = 0; mi < 4; mi++)
        offA[mi] = (wr * 64 + mi * 16 + r) * 32 + swz;
#pragma unroll
    for (int ni = 0; ni < 4; ni++)
        offB[ni] = (wc * 64 + ni * 16 + r) * 32 + swz;

    float4_t acc[4][4];
#pragma unroll
    for (int i = 0; i < 4; i++)
#pragma unroll
        for (int j = 0; j < 4; j++) {
            float4_t z = {0.f, 0.f, 0.f, 0.f};
            acc[i][j] = z;
        }

    // 4 global_load_lds per wave per K-step (2 A + 2 B), each 16B/lane.
#define STAGE(ks, bsel)                                                         \
    {                                                                           \
        const int k0_ = (ks) * 32;                                              \
        short* Ad_ = smem + ((bsel) ? 8192 : 0);                                \
        short* Bd_ = Ad_ + 4096;                                                \
        _Pragma("unroll")                                                       \
        for (int h = 0; h < 2; h++) {                                           \
            __builtin_amdgcn_global_load_lds(                                   \
                (const __attribute__((address_space(1))) unsigned int*)(gA[h] + k0_), \
                (__attribute__((address_space(3))) unsigned int*)(Ad_ + h * 2048 + w * 512), \
                16, 0, 0);                                                      \
            __builtin_amdgcn_global_load_lds(                                   \
                (const __attribute__((address_space(1))) unsigned int*)(gB[h] + k0_), \
                (__attribute__((address_space(3))) unsigned int*)(Bd_ + h * 2048 + w * 512), \
                16, 0, 0);                                                      \
        }                                                                       \
    }

    STAGE(0, 0);
#pragma unroll 1
    for (int ks = 0; ks < 8; ks++) {
        const int cur = ks & 1;
        if (ks < 7) {
            STAGE(ks + 1, cur ^ 1);
            asm volatile("s_waitcnt vmcnt(4)" ::: "memory");
        } else {
            asm volatile("s_waitcnt vmcnt(0)" ::: "memory");
        }
        asm volatile("s_barrier" ::: "memory");

        const short* As_b = smem + (cur ? 8192 : 0);
        const short* Bs_b = As_b + 4096;
        short8_t af[4], bf[4];
#pragma unroll
        for (int mi = 0; mi < 4; mi++)
            af[mi] = *(const short8_t*)&As_b[offA[mi]];
#pragma unroll
        for (int ni = 0; ni < 4; ni++)
            bf[ni] = *(const short8_t*)&Bs_b[offB[ni]];
#pragma unroll
        for (int mi = 0; mi < 4; mi++)
#pragma unroll
            for (int ni = 0; ni < 4; ni++)
                acc[mi][ni] = __builtin_amdgcn_mfma_f32_16x16x32_bf16(
                    af[mi], bf[ni], acc[mi][ni], 0, 0, 0);
        asm volatile("s_barrier" ::: "memory");
    }
#undef STAGE

    // ---- epilogue: bias+relu, LDS-staged coalesced bf16 stores (2 rounds) ----
    short* St = smem;   // 64*136 = 8704 shorts, aliases buffers (K-loop done)

    float bv[4];
#pragma unroll
    for (int ni = 0; ni < 4; ni++)
        bv[ni] = bias[n0 + wc * 64 + ni * 16 + r];

#pragma unroll
    for (int mp = 0; mp < 2; mp++) {
#pragma unroll
        for (int s = 0; s < 2; s++) {
#pragma unroll
            for (int ni = 0; ni < 4; ni++) {
#pragma unroll
                for (int e = 0; e < 4; e++) {
                    const int rl = s * 32 + wr * 16 + q * 4 + e;
                    const int col = wc * 64 + ni * 16 + r;
                    St[rl * 136 + col] =
                        f2bf(fmaxf(acc[mp * 2 + s][ni][e] + bv[ni], 0.f));
                }
            }
        }
        __syncthreads();
        // readout: 1024 chunks of 8 shorts (16B); each thread stores 4
#pragma unroll
        for (int j = 0; j < 4; j++) {
            const int id = t + 256 * j;
            const int rl2 = id >> 4;       // 0..63
            const int ch = id & 15;        // 0..15
            const int s = rl2 >> 5;
            const int rl = rl2 & 31;
            const int grow = m0 + (rl >> 4) * 64 + (mp * 2 + s) * 16 + (rl & 15);
            const short8_t v = *(const short8_t*)&St[rl2 * 136 + ch * 8];
            if (grow < M)
                *(short8_t*)&Y[(size_t)grow * DIM + n0 + ch * 8] = v;
        }
        if (mp == 0) __syncthreads();
    }
}

// ---------------- CSR scan: blocksums -> per-block rescan+write ----------------
// Phase 1: block b reduces cnt[b*1024 .. +1023] -> bsum[b].
__global__ __launch_bounds__(256) void scan_blocksums(
    const int* __restrict__ cnt, int N, int* __restrict__ bsum)
{
    __shared__ int red[256];
    const int t = threadIdx.x;
    const int base = blockIdx.x * 1024 + t * 4;
    int s = 0;
#pragma unroll
    for (int j = 0; j < 4; j++) {
        const int i = base + j;
        if (i < N) s += cnt[i];
    }
    red[t] = s;
    __syncthreads();
#pragma unroll
    for (int off = 128; off > 0; off >>= 1) {
        if (t < off) red[t] += red[t + off];
        __syncthreads();
    }
    if (t == 0) bsum[blockIdx.x] = red[0];
}

// Phase 2 (R10: replaces scan_offsets + scan_phase3): each block re-scans the
// <=64 block-sums LOCALLY (64 ints -- trivial), then scans its own 1024 cnts
// and writes rowptr+cursor. One dispatch fewer, no global exclusive pass.
__global__ __launch_bounds__(256) void scan_write(
    const int* __restrict__ cnt, int N, const int* __restrict__ bsum, int nb,
    int* __restrict__ rowptr, int* __restrict__ cursor)
{
    __shared__ int sb[64];
    __shared__ int sh[256];
    const int t = threadIdx.x;
    if (t < 64) sb[t] = (t < nb) ? bsum[t] : 0;
    __syncthreads();
    for (int off = 1; off < 64; off <<= 1) {
        int v = 0;
        if (t < 64) v = sb[t] + ((t >= off) ? sb[t - off] : 0);
        __syncthreads();
        if (t < 64) sb[t] = v;
        __syncthreads();
    }
    const int run0 = (blockIdx.x == 0) ? 0 : sb[blockIdx.x - 1];
    const int total = sb[nb - 1];

    const int base = blockIdx.x * 1024 + t * 4;
    int v[4];
#pragma unroll
    for (int j = 0; j < 4; j++) {
        const int i = base + j;
        v[j] = (i < N) ? cnt[i] : 0;
    }
    sh[t] = v[0] + v[1] + v[2] + v[3];
    __syncthreads();
    for (int off = 1; off < 256; off <<= 1) {
        const int add = (t >= off) ? sh[t - off] : 0;
        __syncthreads();
        sh[t] += add;
        __syncthreads();
    }
    int run = run0 + ((t == 0) ? 0 : sh[t - 1]);
#pragma unroll
    for (int j = 0; j < 4; j++) {
        const int i = base + j;
        if (i < N) { rowptr[i] = run; cursor[i] = run; }
        run += v[j];
    }
    if ((int)blockIdx.x == nb - 1 && t == 255) rowptr[N] = total;
}

__global__ __launch_bounds__(256) void fill_edges(
    const int* __restrict__ src, const int* __restrict__ dst,
    const int* __restrict__ et, int E, int* __restrict__ cursor,
    unsigned* __restrict__ ep)
{
    const int e = blockIdx.x * blockDim.x + threadIdx.x;
    if (e >= E) return;
    const int pos = atomicAdd(&cursor[dst[e]], 1);
    ep[pos] = (unsigned)src[e] | ((unsigned)et[e] << 16);
}

// -------- aggregate: one dst per HALF-WAVE, fp64 accumulators --------
// R10: aggregate is bound by the per-dst SERIAL chain (rowptr -> ep -> gather
// ~2400cy, one dst at a time per wave). A 512B message row = 32 lanes x 16B,
// so each half-wave owns its own dst: 2 independent chains per wave, no
// cross-half fold.
// R11: accumulate in DOUBLE. fill_edges' atomic cursor makes ep bucket order
// nondeterministic per run; fp32 accumulation order differences then flip
// bf16 rounding boundaries in h1b and cascade through layer 2 (R10 tripwire:
// absmax 5.0 first run -> 8.125 post-timing). fp64 accumulation of bf16-
// valued summands is order-independent to ~2^-53 rel, so the final bf16/f32
// casts are replay-deterministic regardless of edge arrival order.
template <typename OT>
__global__ __launch_bounds__(256) void aggregate2x(
    const unsigned short* __restrict__ yall,   // [R][M][256]
    const unsigned* __restrict__ ep, const int* __restrict__ rowptr,
    OT* __restrict__ out, int M)
{
    const int lane = threadIdx.x & 63;
    const int half = lane >> 5;     // which dst of the pair
    const int cl = lane & 31;       // 16B chunk within message row
    const int wv = (blockIdx.x * blockDim.x + threadIdx.x) >> 6;
    const int nw = (gridDim.x * blockDim.x) >> 6;
    const size_t plane = (size_t)M * DIM;
    const int npair = (M + 1) >> 1;

    for (int pr = wv; pr < npair; pr += nw) {
        const int d = 2 * pr + half;
        const bool live = (d < M);
        double acc[8];
#pragma unroll
        for (int j = 0; j < 8; j++) acc[j] = 0.0;

        int beg = 0, end = 0;
        if (live) { beg = rowptr[d]; end = rowptr[d + 1]; }

        for (int c0 = beg; c0 < end; c0 += 32) {
            const int n = min(32, end - c0);
            const unsigned myep = (c0 + cl < end) ? ep[c0 + cl] : 0u;
            for (int i = 0; i < n; i += 4) {
                short8_t u[4];
#pragma unroll
                for (int j = 0; j < 4; j++) {
                    const unsigned p = __shfl(myep, half * 32 + ((i + j) & 31));
                    // loads always address-safe (myep==0 for OOB lanes)
                    u[j] = *(const short8_t*)(
                        yall + (size_t)(p >> 16) * plane +
                        (size_t)(p & 0xFFFFu) * DIM + cl * 8);
                }
#pragma unroll
                for (int j = 0; j < 4; j++) {
                    if (i + j < n) {
#pragma unroll
                        for (int k = 0; k < 8; k++)
                            acc[k] += (double)bf2f((unsigned short)u[j][k]);
                    }
                }
            }
        }
        if (live) {
            OT* dp = out + (size_t)d * DIM + cl * 8;
            if (sizeof(OT) == 4) {
                *(float4*)((float*)dp) = make_float4(
                    (float)acc[0], (float)acc[1], (float)acc[2], (float)acc[3]);
                *(float4*)((float*)dp + 4) = make_float4(
                    (float)acc[4], (float)acc[5], (float)acc[6], (float)acc[7]);
            } else {
                short8_t v;
#pragma unroll
                for (int j = 0; j < 8; j++) v[j] = (short)f2bf((float)acc[j]);
                *(short8_t*)((unsigned short*)dp) = v;
            }
        }
    }
}

// ---------------- fallback: fp32 vector GEMM + atomic scatter ----------------
__global__ __launch_bounds__(256) void gemm_bias_relu_f32(
    const float* __restrict__ A, const float* __restrict__ B,
    const float* __restrict__ bias, float* __restrict__ Y, int M)
{
    __shared__ float Asf[16][132];
    __shared__ float Bsf[16][128];
    const int t = threadIdx.x;
    const int tx = t & 15, ty = t >> 4;
    const int row0 = blockIdx.x * 128, col0 = blockIdx.y * 128;
    float acc[8][8];
#pragma unroll
    for (int i = 0; i < 8; i++)
#pragma unroll
        for (int j = 0; j < 8; j++) acc[i][j] = 0.f;
    const int arow = t >> 2, akseg = (t & 3) * 4;
    const int bk0 = t >> 5, bcol = (t & 31) * 4;
    for (int k0 = 0; k0 < DIM; k0 += 16) {
#pragma unroll
        for (int h = 0; h < 2; h++) {
            const int row = row0 + arow + h * 64;
            float4 av = (row < M) ? *(const float4*)(A + (size_t)row * DIM + k0 + akseg)
                                  : make_float4(0, 0, 0, 0);
            Asf[akseg + 0][arow + h * 64] = av.x;
            Asf[akseg + 1][arow + h * 64] = av.y;
            Asf[akseg + 2][arow + h * 64] = av.z;
            Asf[akseg + 3][arow + h * 64] = av.w;
        }
#pragma unroll
        for (int h = 0; h < 2; h++) {
            const int krow = bk0 + h * 8;
            *(float4*)&Bsf[krow][bcol] =
                *(const float4*)(B + (size_t)(k0 + krow) * DIM + col0 + bcol);
        }
        __syncthreads();
#pragma unroll
        for (int k = 0; k < 16; k++) {
            float a[8], b[8];
            *(float4*)&a[0] = *(const float4*)&Asf[k][ty * 4];
            *(float4*)&a[4] = *(const float4*)&Asf[k][64 + ty * 4];
            *(float4*)&b[0] = *(const float4*)&Bsf[k][tx * 4];
            *(float4*)&b[4] = *(const float4*)&Bsf[k][64 + tx * 4];
#pragma unroll
            for (int i = 0; i < 8; i++)
#pragma unroll
                for (int j = 0; j < 8; j++) acc[i][j] = fmaf(a[i], b[j], acc[i][j]);
        }
        __syncthreads();
    }
#pragma unroll
    for (int im = 0; im < 2; im++)
#pragma unroll
        for (int i = 0; i < 4; i++) {
            const int row = row0 + im * 64 + ty * 4 + i;
            if (row >= M) continue;
#pragma unroll
            for (int jm = 0; jm < 2; jm++) {
                const int col = col0 + jm * 64 + tx * 4;
                const float4 bb = *(const float4*)(bias + col);
                float4 o;
                o.x = fmaxf(acc[im * 4 + i][jm * 4 + 0] + bb.x, 0.f);
                o.y = fmaxf(acc[im * 4 + i][jm * 4 + 1] + bb.y, 0.f);
                o.z = fmaxf(acc[im * 4 + i][jm * 4 + 2] + bb.z, 0.f);
                o.w = fmaxf(acc[im * 4 + i][jm * 4 + 3] + bb.w, 0.f);
                *(float4*)(Y + (size_t)row * DIM + col) = o;
            }
        }
}

__global__ __launch_bounds__(256) void scatter_rel(
    const float* __restrict__ y, const int* __restrict__ src,
    const int* __restrict__ dst, const int* __restrict__ et,
    int rel, float* __restrict__ out, int n_edges)
{
    const int lane = threadIdx.x & 63;
    const int wave = (blockIdx.x * blockDim.x + threadIdx.x) >> 6;
    const int nwaves = (gridDim.x * blockDim.x) >> 6;
    for (int e = wave; e < n_edges; e += nwaves) {
        if (et[e] != rel) continue;
        const float4 v = *(const float4*)(y + (size_t)src[e] * DIM + lane * 4);
        float* o = out + (size_t)dst[e] * DIM + lane * 4;
        atomicAdd(o + 0, v.x);
        atomicAdd(o + 1, v.y);
        atomicAdd(o + 2, v.z);
        atomicAdd(o + 3, v.w);
    }
}

static inline size_t align16(size_t x) { return (x + 15) & ~(size_t)15; }

extern "C" void kernel_launch(void* const* d_in, const int* in_sizes, int n_in,
                              void* d_out, int out_size, void* d_ws, size_t ws_size,
                              hipStream_t stream)
{
    const float* x  = (const float*)d_in[0];
    const float* W0 = (const float*)d_in[1];
    const float* b0 = (const float*)d_in[2];
    const float* W1 = (const float*)d_in[3];
    const float* b1 = (const float*)d_in[4];
    const int* eidx = (const int*)d_in[5];
    const int* etyp = (const int*)d_in[6];

    const int M = in_sizes[0] / DIM;   // 50000
    const int E = in_sizes[6];         // 800000
    const int* src = eidx;
    const int* dst = eidx + E;
    float* out = (float*)d_out;

    const size_t plane = (size_t)M * DIM;
    const size_t wbytes = (size_t)N_REL * DIM * DIM * 2;

    const size_t need = align16(plane * 2)              // h1b
                      + align16(plane * 2)              // xb
                      + 2 * align16(wbytes)             // Wt0b, Wt1b
                      + align16((size_t)(M + 1) * 4)    // rowptr
                      + 2 * align16((size_t)M * 4)      // cnt, cursor
                      + align16((size_t)256 * 4)        // bsum (block sums)
                      + align16((size_t)E * 4)          // ep
                      + align16((size_t)N_REL * plane * 2);  // yall

    if (M < 65536 && ws_size >= need) {
        char* ws = (char*)d_ws;
        size_t off = 0;
        unsigned short* h1b  = (unsigned short*)(ws + off); off = align16(off + plane * 2);
        unsigned short* xb   = (unsigned short*)(ws + off); off = align16(off + plane * 2);
        unsigned short* Wt0b = (unsigned short*)(ws + off); off = align16(off + wbytes);
        unsigned short* Wt1b = (unsigned short*)(ws + off); off = align16(off + wbytes);
        int* rowptr = (int*)(ws + off); off = align16(off + (size_t)(M + 1) * 4);
        int* cnt    = (int*)(ws + off); off = align16(off + (size_t)M * 4);
        int* cursor = (int*)(ws + off); off = align16(off + (size_t)M * 4);
        int* bsum   = (int*)(ws + off); off = align16(off + (size_t)256 * 4);
        unsigned* ep = (unsigned*)(ws + off); off = align16(off + (size_t)E * 4);
        unsigned short* yall = (unsigned short*)(ws + off);

        // --- prep megakernel: cast + 2 transposes + count_dst in one dispatch
        const int n4 = (int)(plane / 4);
        const int nCast = (n4 + 255) / 256;
        const int nW = 512;                 // 8x8 tiles x 8 rels
        const int nCnt = (E + 255) / 256;
        hipMemsetAsync(cnt, 0, (size_t)M * 4, stream);
        prep_mega<<<nCast + 2 * nW + nCnt, 256, 0, stream>>>(
            x, xb, n4, W0, Wt0b, W1, Wt1b, dst, E, cnt, nCast, nW);

        // --- CSR scan: 2 dispatches (R10: scan_write re-scans <=64 bsums
        // locally, replacing scan_offsets + scan_phase3)
        const int nb = (M + 1023) / 1024;   // <= 64 blocks for M < 65536
        scan_blocksums<<<nb, 256, 0, stream>>>(cnt, M, bsum);
        scan_write<<<nb, 256, 0, stream>>>(cnt, M, bsum, nb, rowptr, cursor);
        fill_edges<<<(E + 255) / 256, 256, 0, stream>>>(src, dst, etyp, E, cursor, ep);

        const int Rtiles = (M + 127) / 128;
        const int octets = (Rtiles + 7) / 8;
        const int ggrid = octets * 16 * 8;
        const int npair = (M + 1) / 2;
        const int agrid = (npair * 64 + 255) / 256;   // 1 dst per half-wave

        // layer 1
        gemm_mfma_bias_relu<<<ggrid, 256, 0, stream>>>(xb, Wt0b, b0, yall, M, Rtiles);
        aggregate2x<unsigned short><<<agrid, 256, 0, stream>>>(yall, ep, rowptr, h1b, M);
        // layer 2
        gemm_mfma_bias_relu<<<ggrid, 256, 0, stream>>>(h1b, Wt1b, b1, yall, M, Rtiles);
        aggregate2x<float><<<agrid, 256, 0, stream>>>(yall, ep, rowptr, out, M);
    } else {
        // fallback: fp32 per-relation GEMM + atomic scatter
        float* h1 = (float*)d_ws;
        float* y  = (float*)d_ws + plane;
        const dim3 gblk(256), ggrid2((M + 127) / 128, DIM / 128);
        hipMemsetAsync(h1, 0, plane * 4, stream);
        for (int r = 0; r < N_REL; r++) {
            gemm_bias_relu_f32<<<ggrid2, gblk, 0, stream>>>(
                x, W0 + (size_t)r * DIM * DIM, b0, y, M);
            scatter_rel<<<1024, 256, 0, stream>>>(y, src, dst, etyp, r, h1, E);
        }
        hipMemsetAsync(out, 0, plane * 4, stream);
        for (int r = 0; r < N_REL; r++) {
            gemm_bias_relu_f32<<<ggrid2, gblk, 0, stream>>>(
                h1, W1 + (size_t)r * DIM * DIM, b1, y, M);
            scatter_rel<<<1024, 256, 0, stream>>>(y, src, dst, etyp, r, out, E);
        }
    }
}

// Round 8
// 469.313 us; speedup vs baseline: 1.3857x; 1.0599x over previous
//
#include <hip/hip_runtime.h>

#define DIM 256
#define N_REL 8
#define NBLK 256     // blocks in build/scatter passes
#define NBH 256      // high-byte bins (dst < 65536)

typedef __attribute__((ext_vector_type(8))) short short8_t;
typedef __attribute__((ext_vector_type(4))) float float4_t;

// ---------------- bf16 helpers (manual, RNE) ----------------
__device__ inline unsigned short f2bf(float f) {
    unsigned u = __float_as_uint(f);
    u += 0x7FFFu + ((u >> 16) & 1u);
    return (unsigned short)(u >> 16);
}
__device__ inline float bf2f(unsigned short h) {
    return __uint_as_float(((unsigned)h) << 16);
}

// ---------------------------------------------------------------------------
// prep megakernel: {cast x->bf16 | transpose W0 | transpose W1}.
// R12: count_dst branch REMOVED (800K device-scope random atomics -- part of
// the persistent ~175us "rest" in every round's accounting; replaced by the
// atomic-free bucket sort below).
// ---------------------------------------------------------------------------
__global__ __launch_bounds__(256) void prep_mega(
    const float* __restrict__ x, unsigned short* __restrict__ xb, int n4,
    const float* __restrict__ W0, unsigned short* __restrict__ Wt0,
    const float* __restrict__ W1, unsigned short* __restrict__ Wt1,
    int nCast, int nW)
{
    __shared__ float tile[32][33];
    const int b = blockIdx.x;
    const int t = threadIdx.x;
    if (b < nCast) {
        const int i = b * 256 + t;
        if (i < n4) {
            const float4 v = ((const float4*)x)[i];
            ushort4 o;
            o.x = f2bf(v.x); o.y = f2bf(v.y); o.z = f2bf(v.z); o.w = f2bf(v.w);
            ((ushort4*)xb)[i] = o;
        }
    } else {
        const int wi = b - nCast;
        const float* W = (wi < nW) ? W0 : W1;
        unsigned short* Wt = (wi < nW) ? Wt0 : Wt1;
        const int bb = (wi < nW) ? wi : wi - nW;
        const int rel = bb >> 6;
        const int bx = bb & 7, by = (bb >> 3) & 7;
        const int i0 = bx * 32, o0 = by * 32;
        const int tx = t & 31, ty = t >> 5;          // (32, 8)
        const float* Wr = W + (size_t)rel * DIM * DIM;
        unsigned short* Wtr = Wt + (size_t)rel * DIM * DIM;
#pragma unroll
        for (int j = 0; j < 4; j++)
            tile[ty + 8 * j][tx] = Wr[(size_t)(i0 + ty + 8 * j) * DIM + o0 + tx];
        __syncthreads();
#pragma unroll
        for (int j = 0; j < 4; j++)
            Wtr[(size_t)(o0 + ty + 8 * j) * DIM + i0 + tx] =
                f2bf(tile[tx][ty + 8 * j]);
    }
}

// ---------------------------------------------------------------------------
// R12 atomic-free CSR build: MSD bucket sort by dst, zero global atomics.
// key u64 = [dst:16 @bit32][et:16 @bit16][src:16 @bit0]; payload (low u32)
// is exactly the ep format (et<<16|src).
// R13: e64a/e64b transients ALIASED into the yall region (yall is written
// only after the sort completes -- stream ordered). Keeps `need` at the
// R11-proven ~262MB footprint; R12's +13MB may have tipped ws_size into the
// untested fallback path (container-failure suspect).
// ---------------------------------------------------------------------------
// Pass A: pack keys + per-block LDS histogram of dst>>8 (plain stores to
// hist[bin*NBLK+blk] -- each slot has exactly one writer).
__global__ __launch_bounds__(256) void build_keys_hist(
    const int* __restrict__ src, const int* __restrict__ dst,
    const int* __restrict__ et, int E,
    unsigned long long* __restrict__ e0, int* __restrict__ hist)
{
    __shared__ int lh[NBH];
    const int t = threadIdx.x, b = blockIdx.x;
    lh[t] = 0;
    __syncthreads();
    const int chunk = (E + NBLK - 1) / NBLK;
    const int lo = b * chunk, hi = min(lo + chunk, E);
    for (int i = lo + t; i < hi; i += 256) {
        const unsigned d = (unsigned)dst[i];
        e0[i] = ((unsigned long long)d << 32) |
                ((unsigned)((et[i] << 16) | src[i]));
        atomicAdd(&lh[d >> 8], 1);          // LDS atomic (fast, banked)
    }
    __syncthreads();
    hist[t * NBLK + b] = lh[t];
}

// Generic exclusive-scan pair (n <= 65536 -> nb <= 64). outArr may alias a
// (each block reads only its own range before writing it).
__global__ __launch_bounds__(256) void scan_g_blocksums(
    const int* __restrict__ a, int n, int* __restrict__ bsum)
{
    __shared__ int red[256];
    const int t = threadIdx.x;
    const int base = blockIdx.x * 1024 + t * 4;
    int s = 0;
#pragma unroll
    for (int j = 0; j < 4; j++) {
        const int i = base + j;
        if (i < n) s += a[i];
    }
    red[t] = s;
    __syncthreads();
#pragma unroll
    for (int off = 128; off > 0; off >>= 1) {
        if (t < off) red[t] += red[t + off];
        __syncthreads();
    }
    if (t == 0) bsum[blockIdx.x] = red[0];
}

__global__ __launch_bounds__(256) void scan_g_write(
    const int* __restrict__ a, int n, const int* __restrict__ bsum, int nb,
    int* __restrict__ outArr, int* __restrict__ totalSlot)
{
    __shared__ int sb[64];
    __shared__ int sh[256];
    const int t = threadIdx.x;
    if (t < 64) sb[t] = (t < nb) ? bsum[t] : 0;
    __syncthreads();
    for (int off = 1; off < 64; off <<= 1) {
        int v = 0;
        if (t < 64) v = sb[t] + ((t >= off) ? sb[t - off] : 0);
        __syncthreads();
        if (t < 64) sb[t] = v;
        __syncthreads();
    }
    const int run0 = (blockIdx.x == 0) ? 0 : sb[blockIdx.x - 1];
    const int total = sb[nb - 1];

    const int base = blockIdx.x * 1024 + t * 4;
    int v[4];
#pragma unroll
    for (int j = 0; j < 4; j++) {
        const int i = base + j;
        v[j] = (i < n) ? a[i] : 0;
    }
    sh[t] = v[0] + v[1] + v[2] + v[3];
    __syncthreads();
    for (int off = 1; off < 256; off <<= 1) {
        const int add = (t >= off) ? sh[t - off] : 0;
        __syncthreads();
        sh[t] += add;
        __syncthreads();
    }
    int run = run0 + ((t == 0) ? 0 : sh[t - 1]);
#pragma unroll
    for (int j = 0; j < 4; j++) {
        const int i = base + j;
        if (i < n) outArr[i] = run;
        run += v[j];
    }
    if (totalSlot && (int)blockIdx.x == nb - 1 && t == 255) *totalSlot = total;
}

// Pass B: scatter into high-byte buckets. Base = scanned hist (stable across
// blocks); local rank via LDS atomic (order within (bin,blk) is run-varying,
// which is safe: aggregate sums in fp64, order-independent -- R11-verified).
__global__ __launch_bounds__(256) void scatter_pass1(
    const unsigned long long* __restrict__ e0, int E,
    const int* __restrict__ histx, unsigned long long* __restrict__ e1)
{
    __shared__ int lbase[NBH];
    __shared__ int lrun[NBH];
    const int t = threadIdx.x, b = blockIdx.x;
    lbase[t] = histx[t * NBLK + b];
    lrun[t] = 0;
    __syncthreads();
    const int chunk = (E + NBLK - 1) / NBLK;
    const int lo = b * chunk, hi = min(lo + chunk, E);
    for (int i = lo + t; i < hi; i += 256) {
        const unsigned long long v = e0[i];
        const int bin = (int)(v >> 40) & 0xFF;
        const int pos = lbase[bin] + atomicAdd(&lrun[bin], 1);
        e1[pos] = v;
    }
}

// Pass C: one block per high-byte bucket; LDS counting sort on dst low byte
// (2 global passes over the L2-hot bucket -- no LDS capacity limit).
// Writes final ep + per-dst cnt (single writer per dst, deterministic).
__global__ __launch_bounds__(256) void bucket_sort(
    const unsigned long long* __restrict__ e1, int E,
    const int* __restrict__ histx,
    unsigned* __restrict__ ep, int* __restrict__ cnt)
{
    __shared__ int lh[256], lincl[256], lexcl[256], lrun[256];
    const int t = threadIdx.x;
    const int h = blockIdx.x;
    const int start = histx[h * NBLK];
    const int end = (h == NBH - 1) ? E : histx[(h + 1) * NBLK];
    if (end <= start) return;            // uniform across block
    lh[t] = 0;
    __syncthreads();
    for (int i = start + t; i < end; i += 256)
        atomicAdd(&lh[(int)(e1[i] >> 32) & 0xFF], 1);
    __syncthreads();
    const int v = lh[t];
    lincl[t] = v;
    __syncthreads();
    for (int off = 1; off < 256; off <<= 1) {
        const int add = (t >= off) ? lincl[t - off] : 0;
        __syncthreads();
        lincl[t] += add;
        __syncthreads();
    }
    lexcl[t] = lincl[t] - v;
    lrun[t] = 0;
    if (v > 0) cnt[(h << 8) | t] = v;    // dst = h*256 + t
    __syncthreads();
    for (int i = start + t; i < end; i += 256) {
        const unsigned long long x = e1[i];
        const int low = (int)(x >> 32) & 0xFF;
        const int pos = lexcl[low] + atomicAdd(&lrun[low], 1);
        ep[start + pos] = (unsigned)(x & 0xFFFFFFFFu);
    }
}

// ---------------------------------------------------------------------------
// Yall[rel][M][256] = relu(Xb @ W[rel] + bias) in bf16.
// Tile 128x128, BK=32, 4 waves of 64x64 (4x4 mfma_f32_16x16x32_bf16).
// R8: global_load_lds width=16 (HBM->LDS DMA), XOR seg swizzle applied BOTH
// to global source and ds_read offset (rule 21) -> conflicts 1.36e7->8e5.
// R11: verified 2-buffer vmcnt(4) schedule (absmax 1.0); R9 2-round epilogue.
// OOB A-rows of the last tile load garbage (in-workspace) but those acc rows
// are never stored (grow<M guard).
// 1-D grid, octet swizzle: rt = (L>>7)*8 | (L&7) pins each row-tile to one
// XCD across all 16 (ntile, rel) combos -> A fetched ~once (FETCH 17.6MB).
// NOTE: epilogue mi-loop MUST be fully unrolled: a runtime index into acc[]
// demotes the accumulator to scratch (R4/R5: 3.7 GB WRITE_SIZE, VGPR 88->64).
// ---------------------------------------------------------------------------
__global__ __launch_bounds__(256) void gemm_mfma_bias_relu(
    const unsigned short* __restrict__ Xb,    // [M][256]
    const unsigned short* __restrict__ Wtb,   // [R][256out][256in]
    const float* __restrict__ bias,           // [256]
    unsigned short* __restrict__ Yall, int M, int Rtiles)
{
    // buf0: As 0..4095 | Bs 4096..8191 ; buf1: As 8192.. | Bs 12288.. (shorts)
    __shared__ __align__(16) short smem[16384];   // 32 KiB

    const unsigned L = blockIdx.x;
    const int xcd = L & 7;
    const unsigned g = L >> 3;
    const int combo = g & 15;                 // (ntile, rel)
    const int rt = (int)((g >> 4) << 3) | xcd;
    if (rt >= Rtiles) return;
    const int m0 = rt * 128;
    const int n0 = (combo & 1) * 128;
    const int rel = combo >> 1;

    const unsigned short* Wt = Wtb + (size_t)rel * DIM * DIM;
    unsigned short* Y = Yall + (size_t)rel * M * DIM;

    const int t = threadIdx.x;
    const int lane = t & 63;
    const int w = t >> 6;
    const int wr = w & 1, wc = w >> 1;
    const int r = lane & 15, q = lane >> 4;

    // ---- staging geometry: chunk c = h*256 + w*64 + lane, c=(row*4+slot) ----
    const int sl = lane & 3;            // 16B slot within 64B row
    const int rsub = lane >> 2;         // 0..15
    const unsigned short* gA[2];
    const unsigned short* gB[2];
#pragma unroll
    for (int h = 0; h < 2; h++) {
        const int row = h * 64 + w * 16 + rsub;          // 0..127
        const int gseg = sl ^ ((row >> 1) & 3);          // pre-swizzled source
        gA[h] = Xb + (size_t)(m0 + row) * DIM + gseg * 8;
        gB[h] = Wt + (size_t)(n0 + row) * DIM + gseg * 8;
    }

    // ---- fragment read offsets (shorts), constant across K-steps ----
    const int swz = (q ^ ((r >> 1) & 3)) * 8;            // swizzled k-segment
    int offA[4], offB[4];
#pragma unroll
    for (int mi = 0; mi < 4; mi++)
        offA[mi] = (wr * 64 + mi * 16 + r) * 32 + swz;
#pragma unroll
    for (int ni = 0; ni < 4; ni++)
        offB[ni] = (wc * 64 + ni * 16 + r) * 32 + swz;

    float4_t acc[4][4];
#pragma unroll
    for (int i = 0; i < 4; i++)
#pragma unroll
        for (int j = 0; j < 4; j++) {
            float4_t z = {0.f, 0.f, 0.f, 0.f};
            acc[i][j] = z;
        }

    // 4 global_load_lds per wave per K-step (2 A + 2 B), each 16B/lane.
#define STAGE(ks, bsel)                                                         \
    {                                                                           \
        const int k0_ = (ks) * 32;                                              \
        short* Ad_ = smem + ((bsel) ? 8192 : 0);                                \
        short* Bd_ = Ad_ + 4096;                                                \
        _Pragma("unroll")                                                       \
        for (int h = 0; h < 2; h++) {                                           \
            __builtin_amdgcn_global_load_lds(                                   \
                (const __attribute__((address_space(1))) unsigned int*)(gA[h] + k0_), \
                (__attribute__((address_space(3))) unsigned int*)(Ad_ + h * 2048 + w * 512), \
                16, 0, 0);                                                      \
            __builtin_amdgcn_global_load_lds(                                   \
                (const __attribute__((address_space(1))) unsigned int*)(gB[h] + k0_), \
                (__attribute__((address_space(3))) unsigned int*)(Bd_ + h * 2048 + w * 512), \
                16, 0, 0);                                                      \
        }                                                                       \
    }

    STAGE(0, 0);
#pragma unroll 1
    for (int ks = 0; ks < 8; ks++) {
        const int cur = ks & 1;
        if (ks < 7) {
            STAGE(ks + 1, cur ^ 1);
            asm volatile("s_waitcnt vmcnt(4)" ::: "memory");
        } else {
            asm volatile("s_waitcnt vmcnt(0)" ::: "memory");
        }
        asm volatile("s_barrier" ::: "memory");

        const short* As_b = smem + (cur ? 8192 : 0);
        const short* Bs_b = As_b + 4096;
        short8_t af[4], bf[4];
#pragma unroll
        for (int mi = 0; mi < 4; mi++)
            af[mi] = *(const short8_t*)&As_b[offA[mi]];
#pragma unroll
        for (int ni = 0; ni < 4; ni++)
            bf[ni] = *(const short8_t*)&Bs_b[offB[ni]];
#pragma unroll
        for (int mi = 0; mi < 4; mi++)
#pragma unroll
            for (int ni = 0; ni < 4; ni++)
                acc[mi][ni] = __builtin_amdgcn_mfma_f32_16x16x32_bf16(
                    af[mi], bf[ni], acc[mi][ni], 0, 0, 0);
        asm volatile("s_barrier" ::: "memory");
    }
#undef STAGE

    // ---- epilogue: bias+relu, LDS-staged coalesced bf16 stores (2 rounds) ----
    short* St = smem;   // 64*136 = 8704 shorts, aliases buffers (K-loop done)

    float bv[4];
#pragma unroll
    for (int ni = 0; ni < 4; ni++)
        bv[ni] = bias[n0 + wc * 64 + ni * 16 + r];

#pragma unroll
    for (int mp = 0; mp < 2; mp++) {
#pragma unroll
        for (int s = 0; s < 2; s++) {
#pragma unroll
            for (int ni = 0; ni < 4; ni++) {
#pragma unroll
                for (int e = 0; e < 4; e++) {
                    const int rl = s * 32 + wr * 16 + q * 4 + e;
                    const int col = wc * 64 + ni * 16 + r;
                    St[rl * 136 + col] =
                        f2bf(fmaxf(acc[mp * 2 + s][ni][e] + bv[ni], 0.f));
                }
            }
        }
        __syncthreads();
        // readout: 1024 chunks of 8 shorts (16B); each thread stores 4
#pragma unroll
        for (int j = 0; j < 4; j++) {
            const int id = t + 256 * j;
            const int rl2 = id >> 4;       // 0..63
            const int ch = id & 15;        // 0..15
            const int s = rl2 >> 5;
            const int rl = rl2 & 31;
            const int grow = m0 + (rl >> 4) * 64 + (mp * 2 + s) * 16 + (rl & 15);
            const short8_t v = *(const short8_t*)&St[rl2 * 136 + ch * 8];
            if (grow < M)
                *(short8_t*)&Y[(size_t)grow * DIM + n0 + ch * 8] = v;
        }
        if (mp == 0) __syncthreads();
    }
}

// -------- aggregate: one dst per HALF-WAVE, fp64 accumulators --------
// R11: fp64 accumulation makes the sum order-independent (~2^-53 rel), so
// run-varying ep order (LDS-atomic ranks in the sort) is replay-safe.
// R11 counters: FETCH 247MB = full yall re-read from HBM at 46% peak ->
// HBM-random-read bound (205MB yall thrashes the 256MB L3). Locality
// restructuring is the future lever here, not concurrency (R9/R10 nulls).
template <typename OT>
__global__ __launch_bounds__(256) void aggregate2x(
    const unsigned short* __restrict__ yall,   // [R][M][256]
    const unsigned* __restrict__ ep, const int* __restrict__ rowptr,
    OT* __restrict__ out, int M)
{
    const int lane = threadIdx.x & 63;
    const int half = lane >> 5;     // which dst of the pair
    const int cl = lane & 31;       // 16B chunk within message row
    const int wv = (blockIdx.x * blockDim.x + threadIdx.x) >> 6;
    const int nw = (gridDim.x * blockDim.x) >> 6;
    const size_t plane = (size_t)M * DIM;
    const int npair = (M + 1) >> 1;

    for (int pr = wv; pr < npair; pr += nw) {
        const int d = 2 * pr + half;
        const bool live = (d < M);
        double acc[8];
#pragma unroll
        for (int j = 0; j < 8; j++) acc[j] = 0.0;

        int beg = 0, end = 0;
        if (live) { beg = rowptr[d]; end = rowptr[d + 1]; }

        for (int c0 = beg; c0 < end; c0 += 32) {
            const int n = min(32, end - c0);
            const unsigned myep = (c0 + cl < end) ? ep[c0 + cl] : 0u;
            for (int i = 0; i < n; i += 4) {
                short8_t u[4];
#pragma unroll
                for (int j = 0; j < 4; j++) {
                    const unsigned p = __shfl(myep, half * 32 + ((i + j) & 31));
                    // loads always address-safe (myep==0 for OOB lanes)
                    u[j] = *(const short8_t*)(
                        yall + (size_t)(p >> 16) * plane +
                        (size_t)(p & 0xFFFFu) * DIM + cl * 8);
                }
#pragma unroll
                for (int j = 0; j < 4; j++) {
                    if (i + j < n) {
#pragma unroll
                        for (int k = 0; k < 8; k++)
                            acc[k] += (double)bf2f((unsigned short)u[j][k]);
                    }
                }
            }
        }
        if (live) {
            OT* dp = out + (size_t)d * DIM + cl * 8;
            if (sizeof(OT) == 4) {
                *(float4*)((float*)dp) = make_float4(
                    (float)acc[0], (float)acc[1], (float)acc[2], (float)acc[3]);
                *(float4*)((float*)dp + 4) = make_float4(
                    (float)acc[4], (float)acc[5], (float)acc[6], (float)acc[7]);
            } else {
                short8_t v;
#pragma unroll
                for (int j = 0; j < 8; j++) v[j] = (short)f2bf((float)acc[j]);
                *(short8_t*)((unsigned short*)dp) = v;
            }
        }
    }
}

// ---------------- fallback: fp32 vector GEMM + atomic scatter ----------------
__global__ __launch_bounds__(256) void gemm_bias_relu_f32(
    const float* __restrict__ A, const float* __restrict__ B,
    const float* __restrict__ bias, float* __restrict__ Y, int M)
{
    __shared__ float Asf[16][132];
    __shared__ float Bsf[16][128];
    const int t = threadIdx.x;
    const int tx = t & 15, ty = t >> 4;
    const int row0 = blockIdx.x * 128, col0 = blockIdx.y * 128;
    float acc[8][8];
#pragma unroll
    for (int i = 0; i < 8; i++)
#pragma unroll
        for (int j = 0; j < 8; j++) acc[i][j] = 0.f;
    const int arow = t >> 2, akseg = (t & 3) * 4;
    const int bk0 = t >> 5, bcol = (t & 31) * 4;
    for (int k0 = 0; k0 < DIM; k0 += 16) {
#pragma unroll
        for (int h = 0; h < 2; h++) {
            const int row = row0 + arow + h * 64;
            float4 av = (row < M) ? *(const float4*)(A + (size_t)row * DIM + k0 + akseg)
                                  : make_float4(0, 0, 0, 0);
            Asf[akseg + 0][arow + h * 64] = av.x;
            Asf[akseg + 1][arow + h * 64] = av.y;
            Asf[akseg + 2][arow + h * 64] = av.z;
            Asf[akseg + 3][arow + h * 64] = av.w;
        }
#pragma unroll
        for (int h = 0; h < 2; h++) {
            const int krow = bk0 + h * 8;
            *(float4*)&Bsf[krow][bcol] =
                *(const float4*)(B + (size_t)(k0 + krow) * DIM + col0 + bcol);
        }
        __syncthreads();
#pragma unroll
        for (int k = 0; k < 16; k++) {
            float a[8], b[8];
            *(float4*)&a[0] = *(const float4*)&Asf[k][ty * 4];
            *(float4*)&a[4] = *(const float4*)&Asf[k][64 + ty * 4];
            *(float4*)&b[0] = *(const float4*)&Bsf[k][tx * 4];
            *(float4*)&b[4] = *(const float4*)&Bsf[k][64 + tx * 4];
#pragma unroll
            for (int i = 0; i < 8; i++)
#pragma unroll
                for (int j = 0; j < 8; j++) acc[i][j] = fmaf(a[i], b[j], acc[i][j]);
        }
        __syncthreads();
    }
#pragma unroll
    for (int im = 0; im < 2; im++)
#pragma unroll
        for (int i = 0; i < 4; i++) {
            const int row = row0 + im * 64 + ty * 4 + i;
            if (row >= M) continue;
#pragma unroll
            for (int jm = 0; jm < 2; jm++) {
                const int col = col0 + jm * 64 + tx * 4;
                const float4 bb = *(const float4*)(bias + col);
                float4 o;
                o.x = fmaxf(acc[im * 4 + i][jm * 4 + 0] + bb.x, 0.f);
                o.y = fmaxf(acc[im * 4 + i][jm * 4 + 1] + bb.y, 0.f);
                o.z = fmaxf(acc[im * 4 + i][jm * 4 + 2] + bb.z, 0.f);
                o.w = fmaxf(acc[im * 4 + i][jm * 4 + 3] + bb.w, 0.f);
                *(float4*)(Y + (size_t)row * DIM + col) = o;
            }
        }
}

__global__ __launch_bounds__(256) void scatter_rel(
    const float* __restrict__ y, const int* __restrict__ src,
    const int* __restrict__ dst, const int* __restrict__ et,
    int rel, float* __restrict__ out, int n_edges)
{
    const int lane = threadIdx.x & 63;
    const int wave = (blockIdx.x * blockDim.x + threadIdx.x) >> 6;
    const int nwaves = (gridDim.x * blockDim.x) >> 6;
    for (int e = wave; e < n_edges; e += nwaves) {
        if (et[e] != rel) continue;
        const float4 v = *(const float4*)(y + (size_t)src[e] * DIM + lane * 4);
        float* o = out + (size_t)dst[e] * DIM + lane * 4;
        atomicAdd(o + 0, v.x);
        atomicAdd(o + 1, v.y);
        atomicAdd(o + 2, v.z);
        atomicAdd(o + 3, v.w);
    }
}

static inline size_t align16(size_t x) { return (x + 15) & ~(size_t)15; }

extern "C" void kernel_launch(void* const* d_in, const int* in_sizes, int n_in,
                              void* d_out, int out_size, void* d_ws, size_t ws_size,
                              hipStream_t stream)
{
    const float* x  = (const float*)d_in[0];
    const float* W0 = (const float*)d_in[1];
    const float* b0 = (const float*)d_in[2];
    const float* W1 = (const float*)d_in[3];
    const float* b1 = (const float*)d_in[4];
    const int* eidx = (const int*)d_in[5];
    const int* etyp = (const int*)d_in[6];

    const int M = in_sizes[0] / DIM;   // 50000
    const int E = in_sizes[6];         // 800000
    const int* src = eidx;
    const int* dst = eidx + E;
    float* out = (float*)d_out;

    const size_t plane = (size_t)M * DIM;
    const size_t wbytes = (size_t)N_REL * DIM * DIM * 2;
    const size_t yall_bytes = (size_t)N_REL * plane * 2;   // 204.8MB

    // R13: e64a/e64b (2*E*8 = 12.8MB) live INSIDE the yall region -- they are
    // dead before the first GEMM writes yall. `need` equals R11's proven
    // footprint (+hist 256KB, -cursor 200KB).
    const size_t need = align16(plane * 2)              // h1b
                      + align16(plane * 2)              // xb
                      + 2 * align16(wbytes)             // Wt0b, Wt1b
                      + align16((size_t)(M + 1) * 4)    // rowptr
                      + align16((size_t)M * 4)          // cnt
                      + align16((size_t)256 * 4)        // bsum
                      + align16((size_t)NBH * NBLK * 4) // hist
                      + align16((size_t)E * 4)          // ep
                      + align16(yall_bytes);            // yall (e64a/e64b alias)

    if (M < 65536 && ws_size >= need && yall_bytes >= 2 * (size_t)E * 8) {
        char* ws = (char*)d_ws;
        size_t off = 0;
        unsigned short* h1b  = (unsigned short*)(ws + off); off = align16(off + plane * 2);
        unsigned short* xb   = (unsigned short*)(ws + off); off = align16(off + plane * 2);
        unsigned short* Wt0b = (unsigned short*)(ws + off); off = align16(off + wbytes);
        unsigned short* Wt1b = (unsigned short*)(ws + off); off = align16(off + wbytes);
        int* rowptr = (int*)(ws + off); off = align16(off + (size_t)(M + 1) * 4);
        int* cnt    = (int*)(ws + off); off = align16(off + (size_t)M * 4);
        int* bsum   = (int*)(ws + off); off = align16(off + (size_t)256 * 4);
        int* hist   = (int*)(ws + off); off = align16(off + (size_t)NBH * NBLK * 4);
        unsigned* ep = (unsigned*)(ws + off); off = align16(off + (size_t)E * 4);
        unsigned short* yall = (unsigned short*)(ws + off);
        unsigned long long* e64a = (unsigned long long*)yall;   // transient
        unsigned long long* e64b = e64a + E;                    // transient

        // --- prep megakernel: cast + 2 transposes (no atomics anymore)
        const int n4 = (int)(plane / 4);
        const int nCast = (n4 + 255) / 256;
        const int nW = 512;                 // 8x8 tiles x 8 rels
        prep_mega<<<nCast + 2 * nW, 256, 0, stream>>>(
            x, xb, n4, W0, Wt0b, W1, Wt1b, nCast, nW);

        // --- R12 atomic-free CSR build: MSD bucket sort by dst
        hipMemsetAsync(cnt, 0, (size_t)M * 4, stream);
        build_keys_hist<<<NBLK, 256, 0, stream>>>(src, dst, etyp, E, e64a, hist);
        const int nhist = NBH * NBLK;                      // 65536
        const int nbh = (nhist + 1023) / 1024;             // 64
        scan_g_blocksums<<<nbh, 256, 0, stream>>>(hist, nhist, bsum);
        scan_g_write<<<nbh, 256, 0, stream>>>(hist, nhist, bsum, nbh, hist, (int*)nullptr);
        scatter_pass1<<<NBLK, 256, 0, stream>>>(e64a, E, hist, e64b);
        bucket_sort<<<NBH, 256, 0, stream>>>(e64b, E, hist, ep, cnt);
        const int nb = (M + 1023) / 1024;                  // 49
        scan_g_blocksums<<<nb, 256, 0, stream>>>(cnt, M, bsum);
        scan_g_write<<<nb, 256, 0, stream>>>(cnt, M, bsum, nb, rowptr, &rowptr[M]);

        const int Rtiles = (M + 127) / 128;
        const int octets = (Rtiles + 7) / 8;
        const int ggrid = octets * 16 * 8;
        const int npair = (M + 1) / 2;
        const int agrid = (npair * 64 + 255) / 256;   // 1 dst per half-wave

        // layer 1 (gemm overwrites the e64 region -- sort is complete by now)
        gemm_mfma_bias_relu<<<ggrid, 256, 0, stream>>>(xb, Wt0b, b0, yall, M, Rtiles);
        aggregate2x<unsigned short><<<agrid, 256, 0, stream>>>(yall, ep, rowptr, h1b, M);
        // layer 2
        gemm_mfma_bias_relu<<<ggrid, 256, 0, stream>>>(h1b, Wt1b, b1, yall, M, Rtiles);
        aggregate2x<float><<<agrid, 256, 0, stream>>>(yall, ep, rowptr, out, M);
    } else {
        // fallback: fp32 per-relation GEMM + atomic scatter
        float* h1 = (float*)d_ws;
        float* y  = (float*)d_ws + plane;
        const dim3 gblk(256), ggrid2((M + 127) / 128, DIM / 128);
        hipMemsetAsync(h1, 0, plane * 4, stream);
        for (int r = 0; r < N_REL; r++) {
            gemm_bias_relu_f32<<<ggrid2, gblk, 0, stream>>>(
                x, W0 + (size_t)r * DIM * DIM, b0, y, M);
            scatter_rel<<<1024, 256, 0, stream>>>(y, src, dst, etyp, r, h1, E);
        }
        hipMemsetAsync(out, 0, plane * 4, stream);
        for (int r = 0; r < N_REL; r++) {
            gemm_bias_relu_f32<<<ggrid2, gblk, 0, stream>>>(
                h1, W1 + (size_t)r * DIM * DIM, b1, y, M);
            scatter_rel<<<1024, 256, 0, stream>>>(y, src, dst, etyp, r, out, E);
        }
    }
}